// Round 4
// baseline (282.115 us; speedup 1.0000x reference)
//
#include <hip/hip_runtime.h>
#include <math.h>

#define NQ 16384
#define NS 4096
#define NCH 256
#define NP 16
#define BIGD 1e8f
#define EPSW 1e-8f

typedef __attribute__((ext_vector_type(8))) short short8;
typedef __attribute__((ext_vector_type(4))) float f32x4;

static __device__ __forceinline__ unsigned short f2bf(float x) {
    unsigned u = __float_as_uint(x);
    unsigned r = (u + 0x7fff + ((u >> 16) & 1)) >> 16;   // RNE
    return (unsigned short)r;
}
static __device__ __forceinline__ float bf2f(unsigned short u) {
    return __uint_as_float(((unsigned)u) << 16);
}

// ------------------------------------------------------- piece bucketing ---
// Stable bucket of set2 points by piece id: bpts[pos] = {x,y,z,orig_idx},
// boff[p]..boff[p+1] is piece p's range. Stability preserves index order
// (needed for top_k tie-break semantics).
__global__ __launch_bounds__(1024)
void bucket_kernel(const float* __restrict__ xyz2, const int* __restrict__ pid2,
                   float4* __restrict__ bpts, int* __restrict__ boff)
{
    __shared__ int spid[NS];
    __shared__ int segcnt[64][NP];
    __shared__ int segbase[64][NP];
    __shared__ int poff[NP + 1];
    const int t = threadIdx.x;
    for (int i = t; i < NS; i += 1024) spid[i] = pid2[i];
    __syncthreads();
    {   // histogram per (segment of 64 points, piece)
        const int seg = t >> 4, p = t & 15;
        int c = 0;
        const int b = seg * 64;
        for (int i = 0; i < 64; ++i) c += (spid[b + i] == p);
        segcnt[seg][p] = c;
    }
    __syncthreads();
    if (t < NP) {       // exclusive prefix over segments, per piece
        int run = 0;
        for (int s = 0; s < 64; ++s) { segbase[s][t] = run; run += segcnt[s][t]; }
        poff[t] = run;  // piece total (temp)
    }
    __syncthreads();
    if (t == 0) {
        int run = 0;
        for (int p = 0; p < NP; ++p) { int c = poff[p]; poff[p] = run; run += c; }
        poff[NP] = run;
    }
    __syncthreads();
    if (t <= NP) boff[t] = poff[t];
    {   // stable scatter: thread (seg,p) walks its segment in order
        const int seg = t >> 4, p = t & 15;
        int pos = poff[p] + segbase[seg][p];
        const int b = seg * 64;
        for (int i = 0; i < 64; ++i) {
            const int gi = b + i;
            if (spid[gi] == p) {
                bpts[pos] = make_float4(xyz2[gi], xyz2[NS + gi], xyz2[2 * NS + gi],
                                        __int_as_float(gi));
                ++pos;
            }
        }
    }
}

// ---------------------------------------------------------------- KNN ------
// 16 threads per query scan only the query's piece bucket (avg 256 pts),
// then butterfly-merge top-3 lists with lexicographic (d, idx) compare.
#define LEXLT(d, j, e, je) ((d) < (e) || ((d) == (e) && (j) < (je)))

__global__ __launch_bounds__(256)
void knn_kernel(const float* __restrict__ xyz1, const int* __restrict__ pid1,
                const float4* __restrict__ bpts, const int* __restrict__ boff,
                int* __restrict__ oidx, float* __restrict__ ow)
{
    const int t = blockIdx.x * 256 + threadIdx.x;
    const int q = t >> 4;
    const int k = t & 15;
    const float qx = xyz1[q], qy = xyz1[NQ + q], qz = xyz1[2 * NQ + q];
    const int p = pid1[q];
    const int s0 = boff[p], s1 = boff[p + 1];

    float e0 = INFINITY, e1 = INFINITY, e2 = INFINITY;
    int j0 = 0, j1 = 0, j2 = 0;
    for (int i = s0 + k; i < s1; i += 16) {
        float4 pt = bpts[i];
        const float dx = pt.x - qx, dy = pt.y - qy, dz = pt.z - qz;
        const float d = fmaf(dx, dx, fmaf(dy, dy, dz * dz));
        const int oi = __float_as_int(pt.w);
        const bool b0 = LEXLT(d, oi, e0, j0), b1 = LEXLT(d, oi, e1, j1),
                   b2 = LEXLT(d, oi, e2, j2);
        e2 = b2 ? (b1 ? e1 : d) : e2;  j2 = b2 ? (b1 ? j1 : oi) : j2;
        e1 = b1 ? (b0 ? e0 : d) : e1;  j1 = b1 ? (b0 ? j0 : oi) : j1;
        e0 = b0 ? d : e0;              j0 = b0 ? oi : j0;
    }
    #pragma unroll
    for (int m = 1; m <= 8; m <<= 1) {
        float f[3]; int gi[3];
        f[0] = __shfl_xor(e0, m); gi[0] = __shfl_xor(j0, m);
        f[1] = __shfl_xor(e1, m); gi[1] = __shfl_xor(j1, m);
        f[2] = __shfl_xor(e2, m); gi[2] = __shfl_xor(j2, m);
        #pragma unroll
        for (int c = 0; c < 3; ++c) {
            const float d = f[c]; const int oi = gi[c];
            const bool b0 = LEXLT(d, oi, e0, j0), b1 = LEXLT(d, oi, e1, j1),
                       b2 = LEXLT(d, oi, e2, j2);
            e2 = b2 ? (b1 ? e1 : d) : e2;  j2 = b2 ? (b1 ? j1 : oi) : j2;
            e1 = b1 ? (b0 ? e0 : d) : e1;  j1 = b1 ? (b0 ? j0 : oi) : j1;
            e0 = b0 ? d : e0;              j0 = b0 ? oi : j0;
        }
    }
    if (k == 0) {
        if (isinf(e0)) { j0 = 0;  e0 = BIGD; }
        if (isinf(e1)) { j1 = j0; e1 = BIGD; }
        if (isinf(e2)) { j2 = j0; e2 = BIGD; }
        const float w0 = 1.f / (e0 + EPSW), w1 = 1.f / (e1 + EPSW), w2 = 1.f / (e2 + EPSW);
        const float inv = 1.f / (w0 + w1 + w2);
        oidx[q * 3 + 0] = j0; oidx[q * 3 + 1] = j1; oidx[q * 3 + 2] = j2;
        ow[q * 3 + 0] = w0 * inv; ow[q * 3 + 1] = w1 * inv; ow[q * 3 + 2] = w2 * inv;
    }
}

// ----------------------------------------------- weights fp32 -> bf16 ------
__global__ __launch_bounds__(256)
void cvtw_kernel(const float* __restrict__ w0, const float* __restrict__ w1,
                 unsigned short* __restrict__ o0, unsigned short* __restrict__ o1)
{
    const int i = blockIdx.x * 256 + threadIdx.x;
    const float* src; unsigned short* dst; int j;
    if (i < 32768) { src = w0; dst = o0; j = i; }
    else           { src = w1; dst = o1; j = i - 32768; }
    float4 v = ((const float4*)src)[j];
    ushort4 o;
    o.x = f2bf(v.x); o.y = f2bf(v.y); o.z = f2bf(v.z); o.w = f2bf(v.w);
    ((ushort4*)dst)[j] = o;
}

// -------------------- [C][srcN] fp32 -> dst[n][kt] bf16 (64x64 tiles) ------
__global__ __launch_bounds__(256)
void tcvt_kernel(const float* __restrict__ src, int srcN,
                 unsigned short* __restrict__ dst, int kt, int coff)
{
    __shared__ float tile[64][65];
    const int cb = blockIdx.x * 64;
    const int nb = blockIdx.y * 64;
    #pragma unroll
    for (int rnd = 0; rnd < 4; ++rnd) {
        const int r = rnd * 16 + (threadIdx.x >> 4);
        const int c4 = (threadIdx.x & 15) * 4;
        float4 v = *(const float4*)&src[(size_t)(cb + r) * srcN + nb + c4];
        tile[r][c4 + 0] = v.x; tile[r][c4 + 1] = v.y;
        tile[r][c4 + 2] = v.z; tile[r][c4 + 3] = v.w;
    }
    __syncthreads();
    #pragma unroll
    for (int half = 0; half < 2; ++half) {
        const int p  = (threadIdx.x >> 3) + half * 32;
        const int cg = threadIdx.x & 7;
        ushort4 o0, o1;
        o0.x = f2bf(tile[cg * 8 + 0][p]); o0.y = f2bf(tile[cg * 8 + 1][p]);
        o0.z = f2bf(tile[cg * 8 + 2][p]); o0.w = f2bf(tile[cg * 8 + 3][p]);
        o1.x = f2bf(tile[cg * 8 + 4][p]); o1.y = f2bf(tile[cg * 8 + 5][p]);
        o1.z = f2bf(tile[cg * 8 + 6][p]); o1.w = f2bf(tile[cg * 8 + 7][p]);
        ushort4* d = (ushort4*)&dst[(size_t)(nb + p) * kt + coff + cb + cg * 8];
        d[0] = o0; d[1] = o1;
    }
}

// ----------------------- interp fused into Xt rows (bf16) ------------------
// one wave per point: Xt[n][256+c] = sum_k w[k] * p2Tb[idx[k]][c]
__global__ __launch_bounds__(256)
void interp_kernel(const unsigned short* __restrict__ p2Tb,
                   const int* __restrict__ oidx, const float* __restrict__ ow,
                   unsigned short* __restrict__ Xt)
{
    const int n = (blockIdx.x * 256 + threadIdx.x) >> 6;
    const int l = threadIdx.x & 63;
    const int i0 = oidx[n * 3 + 0], i1 = oidx[n * 3 + 1], i2 = oidx[n * 3 + 2];
    const float w0 = ow[n * 3 + 0], w1 = ow[n * 3 + 1], w2 = ow[n * 3 + 2];
    ushort4 a = *(const ushort4*)&p2Tb[(size_t)i0 * 256 + l * 4];
    ushort4 b = *(const ushort4*)&p2Tb[(size_t)i1 * 256 + l * 4];
    ushort4 c = *(const ushort4*)&p2Tb[(size_t)i2 * 256 + l * 4];
    ushort4 o;
    o.x = f2bf(w0 * bf2f(a.x) + w1 * bf2f(b.x) + w2 * bf2f(c.x));
    o.y = f2bf(w0 * bf2f(a.y) + w1 * bf2f(b.y) + w2 * bf2f(c.y));
    o.z = f2bf(w0 * bf2f(a.z) + w1 * bf2f(b.z) + w2 * bf2f(c.z));
    o.w = f2bf(w0 * bf2f(a.w) + w1 * bf2f(b.w) + w2 * bf2f(c.w));
    *(ushort4*)&Xt[(size_t)n * 512 + 256 + l * 4] = o;
}

// ------------------------------------------------------------- MFMA GEMM ---
// Y[n][m] (bf16) = (W[256][K] @ X[K][:])^T for a 32-point slab; also
// atomically accumulates per-channel sum / sumsq of the fp32 results.
// LOAD_DIRECT: B staged via global_load_lds from Xt[N][K] (pre-swizzled src).
// else: B reg-staged from Ysrc[N][256] bf16 applying relu(v*sc+sh) with
// sc/sh derived in-block from (sum_in,sq_in,g,bt).
template<int K, bool LOAD_DIRECT>
__global__ __launch_bounds__(256)
void mgemm_kernel(const unsigned short* __restrict__ Wb,
                  const unsigned short* __restrict__ Xsrc,
                  const float* __restrict__ sum_in, const float* __restrict__ sq_in,
                  const float* __restrict__ g, const float* __restrict__ bt,
                  unsigned short* __restrict__ Yout,
                  float* __restrict__ sum_out, float* __restrict__ sq_out)
{
    constexpr int K2 = K * 2;                     // row bytes
    __shared__ unsigned char sB[32 * K2];
    __shared__ float scs[256], shs[256];
    const int tid = threadIdx.x;
    const int n0 = blockIdx.x * 32;

    if (!LOAD_DIRECT) {
        const float mean = sum_in[tid] * (1.f / NQ);
        const float var  = sq_in[tid] * (1.f / NQ) - mean * mean;
        const float rs = rsqrtf(var + 1e-5f);
        const float s = g[tid] * rs;
        scs[tid] = s; shs[tid] = bt[tid] - mean * s;
        __syncthreads();
        const int row = tid >> 3;
        const int cb0 = (tid & 7) * 64;           // byte col base
        #pragma unroll
        for (int ch = 0; ch < 4; ++ch) {
            const int cb = cb0 + ch * 16;
            const short8 v = *(const short8*)&Xsrc[(size_t)(n0 + row) * 256 + cb / 2];
            ushort4 lo, hi;
            const int c = cb / 2;
            lo.x = f2bf(fmaxf(fmaf(bf2f((unsigned short)v[0]), scs[c+0], shs[c+0]), 0.f));
            lo.y = f2bf(fmaxf(fmaf(bf2f((unsigned short)v[1]), scs[c+1], shs[c+1]), 0.f));
            lo.z = f2bf(fmaxf(fmaf(bf2f((unsigned short)v[2]), scs[c+2], shs[c+2]), 0.f));
            lo.w = f2bf(fmaxf(fmaf(bf2f((unsigned short)v[3]), scs[c+3], shs[c+3]), 0.f));
            hi.x = f2bf(fmaxf(fmaf(bf2f((unsigned short)v[4]), scs[c+4], shs[c+4]), 0.f));
            hi.y = f2bf(fmaxf(fmaf(bf2f((unsigned short)v[5]), scs[c+5], shs[c+5]), 0.f));
            hi.z = f2bf(fmaxf(fmaf(bf2f((unsigned short)v[6]), scs[c+6], shs[c+6]), 0.f));
            hi.w = f2bf(fmaxf(fmaf(bf2f((unsigned short)v[7]), scs[c+7], shs[c+7]), 0.f));
            unsigned char* d = &sB[row * K2 + (cb ^ ((row & 7) << 4))];
            ((ushort4*)d)[0] = lo; ((ushort4*)d)[1] = hi;
        }
    } else {
        constexpr int ROUNDS = (32 * K2 / 16) / 256;
        #pragma unroll
        for (int j = 0; j < ROUNDS; ++j) {
            const int p   = (j * 256 + tid) * 16;
            const int row = p >> 10;              // K==512 only
            const int c   = p & (K2 - 1);
            const int q   = c ^ ((row & 7) << 4);
            const char* gp = (const char*)(Xsrc + (size_t)(n0 + row) * K) + q;
            __builtin_amdgcn_global_load_lds(
                (const __attribute__((address_space(1))) void*)gp,
                (__attribute__((address_space(3))) void*)(sB + p), 16, 0, 0);
        }
    }
    __syncthreads();

    const int w = tid >> 6, l = tid & 63;
    const int lr = l & 15, lk = l >> 4;
    f32x4 acc[4][2] = {};
    #pragma unroll
    for (int ks = 0; ks < K / 32; ++ks) {
        short8 b[2];
        #pragma unroll
        for (int nf = 0; nf < 2; ++nf) {
            const int r = nf * 16 + lr;
            const int cbyte = ks * 64 + lk * 16;
            b[nf] = *(const short8*)&sB[r * K2 + (cbyte ^ ((r & 7) << 4))];
        }
        #pragma unroll
        for (int mf = 0; mf < 4; ++mf) {
            const int m = w * 64 + mf * 16 + lr;
            const short8 a = *(const short8*)&Wb[(size_t)m * K + ks * 32 + lk * 8];
            #pragma unroll
            for (int nf = 0; nf < 2; ++nf)
                acc[mf][nf] = __builtin_amdgcn_mfma_f32_16x16x32_bf16(
                                  a, b[nf], acc[mf][nf], 0, 0, 0);
        }
    }
    // epilogue: bf16 store + fused per-channel stats
    float csum[16], csq[16];
    #pragma unroll
    for (int mf = 0; mf < 4; ++mf) {
        #pragma unroll
        for (int nf = 0; nf < 2; ++nf) {
            const int n = n0 + nf * 16 + lr;
            const int moff = w * 64 + mf * 16 + lk * 4;
            ushort4 o;
            o.x = f2bf(acc[mf][nf][0]); o.y = f2bf(acc[mf][nf][1]);
            o.z = f2bf(acc[mf][nf][2]); o.w = f2bf(acc[mf][nf][3]);
            *(ushort4*)&Yout[(size_t)n * 256 + moff] = o;
        }
        #pragma unroll
        for (int r2 = 0; r2 < 4; ++r2) {
            const float v0 = acc[mf][0][r2], v1 = acc[mf][1][r2];
            csum[mf * 4 + r2] = v0 + v1;
            csq [mf * 4 + r2] = v0 * v0 + v1 * v1;
        }
    }
    #pragma unroll
    for (int m = 1; m <= 8; m <<= 1) {
        #pragma unroll
        for (int i = 0; i < 16; ++i) {
            csum[i] += __shfl_xor(csum[i], m);
            csq[i]  += __shfl_xor(csq[i], m);
        }
    }
    if (lr == 0) {
        const int mb = w * 64 + lk * 4;
        #pragma unroll
        for (int mf = 0; mf < 4; ++mf)
            #pragma unroll
            for (int r2 = 0; r2 < 4; ++r2) {
                atomicAdd(&sum_out[mb + mf * 16 + r2], csum[mf * 4 + r2]);
                atomicAdd(&sq_out [mb + mf * 16 + r2], csq [mf * 4 + r2]);
            }
    }
}

// --------------- final: BN2 + relu + transpose [N][256] -> out [256][NQ] ---
__global__ __launch_bounds__(256)
void bnt_kernel(const unsigned short* __restrict__ Y, const float* __restrict__ sum,
                const float* __restrict__ sq, const float* __restrict__ g,
                const float* __restrict__ bt, float* __restrict__ out)
{
    __shared__ float tile[64][65];
    __shared__ float scs[64], shs[64];
    const int t = threadIdx.x;
    const int cb = blockIdx.x * 64;
    const int nb = blockIdx.y * 64;
    if (t < 64) {
        const int c = cb + t;
        const float mean = sum[c] * (1.f / NQ);
        const float var  = sq[c] * (1.f / NQ) - mean * mean;
        const float rs = rsqrtf(var + 1e-5f);
        const float s = g[c] * rs;
        scs[t] = s; shs[t] = bt[c] - mean * s;
    }
    __syncthreads();
    #pragma unroll
    for (int rnd = 0; rnd < 4; ++rnd) {
        const int nl = rnd * 16 + (t >> 4);
        const int c4 = (t & 15) * 4;
        ushort4 v = *(const ushort4*)&Y[(size_t)(nb + nl) * 256 + cb + c4];
        tile[c4 + 0][nl] = fmaxf(fmaf(bf2f(v.x), scs[c4 + 0], shs[c4 + 0]), 0.f);
        tile[c4 + 1][nl] = fmaxf(fmaf(bf2f(v.y), scs[c4 + 1], shs[c4 + 1]), 0.f);
        tile[c4 + 2][nl] = fmaxf(fmaf(bf2f(v.z), scs[c4 + 2], shs[c4 + 2]), 0.f);
        tile[c4 + 3][nl] = fmaxf(fmaf(bf2f(v.w), scs[c4 + 3], shs[c4 + 3]), 0.f);
    }
    __syncthreads();
    const int cl = t >> 2, qq = t & 3;
    float* orow = out + (size_t)(cb + cl) * NQ + nb + qq * 16;
    #pragma unroll
    for (int k = 0; k < 4; ++k) {
        float4 v = make_float4(tile[cl][qq * 16 + k * 4 + 0], tile[cl][qq * 16 + k * 4 + 1],
                               tile[cl][qq * 16 + k * 4 + 2], tile[cl][qq * 16 + k * 4 + 3]);
        *(float4*)&orow[k * 4] = v;
    }
}

// ------------------------------------------------------------------ launch -
extern "C" void kernel_launch(void* const* d_in, const int* in_sizes, int n_in,
                              void* d_out, int out_size, void* d_ws, size_t ws_size,
                              hipStream_t stream)
{
    const float* xyz1    = (const float*)d_in[0];
    const float* xyz2    = (const float*)d_in[1];
    const int*   pid1    = (const int*)d_in[2];
    const int*   pid2    = (const int*)d_in[3];
    const float* points1 = (const float*)d_in[4];
    const float* points2 = (const float*)d_in[5];
    const float* w0      = (const float*)d_in[6];
    const float* g0      = (const float*)d_in[8];
    const float* bt0     = (const float*)d_in[9];
    const float* w1      = (const float*)d_in[10];
    const float* g1      = (const float*)d_in[12];
    const float* bt1     = (const float*)d_in[13];
    float* out = (float*)d_out;

    char* ws = (char*)d_ws;
    int*            boff  = (int*)(ws + 0);                  // 128 B
    float*          sums  = (float*)(ws + 128);              // 4 KB: sum0,sq0,sum1,sq1
    float*          sum0  = sums, *sq0 = sums + 256, *sum1 = sums + 512, *sq1 = sums + 768;
    int*            idxb  = (int*)(ws + 8192);               // 192 KB
    float*          wb    = (float*)(ws + 8192 + 196608);    // 192 KB
    unsigned short* Wb0   = (unsigned short*)(ws + 8192 + 393216);   // 256 KB
    unsigned short* Wb1   = (unsigned short*)(ws + 8192 + 655360);   // 128 KB
    float4*         bpts  = (float4*)(ws + 8192 + 786432);   // 64 KB
    unsigned short* p2Tb  = (unsigned short*)(ws + 1048576); // 2 MB
    unsigned short* Xt    = (unsigned short*)(ws + 1048576 + 2097152);            // 16 MB
    unsigned short* y0Tb  = (unsigned short*)(ws + 1048576 + 2097152 + 16777216); // 8 MB
    unsigned short* y1Tb  = (unsigned short*)(ws + 1048576 + 2097152 + 25165824); // 8 MB

    hipMemsetAsync(sums, 0, 4096, stream);
    bucket_kernel<<<1, 1024, 0, stream>>>(xyz2, pid2, bpts, boff);
    knn_kernel<<<NQ * 16 / 256, 256, 0, stream>>>(xyz1, pid1, bpts, boff, idxb, wb);
    cvtw_kernel<<<192, 256, 0, stream>>>(w0, w1, Wb0, Wb1);
    tcvt_kernel<<<dim3(4, NS / 64), 256, 0, stream>>>(points2, NS, p2Tb, 256, 0);
    tcvt_kernel<<<dim3(4, NQ / 64), 256, 0, stream>>>(points1, NQ, Xt, 512, 0);
    interp_kernel<<<NQ * 64 / 256, 256, 0, stream>>>(p2Tb, idxb, wb, Xt);
    mgemm_kernel<512, true><<<NQ / 32, 256, 0, stream>>>(
        Wb0, Xt, nullptr, nullptr, nullptr, nullptr, y0Tb, sum0, sq0);
    mgemm_kernel<256, false><<<NQ / 32, 256, 0, stream>>>(
        Wb1, y0Tb, sum0, sq0, g0, bt0, y1Tb, sum1, sq1);
    bnt_kernel<<<dim3(4, NQ / 64), 256, 0, stream>>>(y1Tb, sum1, sq1, g1, bt1, out);
}

// Round 5
// 205.307 us; speedup vs baseline: 1.3741x; 1.3741x over previous
//
#include <hip/hip_runtime.h>
#include <math.h>

#define NQ 16384
#define NS 4096
#define NCH 256
#define NP 16
#define BIGD 1e8f
#define EPSW 1e-8f

typedef __attribute__((ext_vector_type(8))) short short8;
typedef __attribute__((ext_vector_type(4))) float f32x4;

static __device__ __forceinline__ unsigned short f2bf(float x) {
    unsigned u = __float_as_uint(x);
    unsigned r = (u + 0x7fff + ((u >> 16) & 1)) >> 16;   // RNE
    return (unsigned short)r;
}
static __device__ __forceinline__ float bf2f(unsigned short u) {
    return __uint_as_float(((unsigned)u) << 16);
}

// ------------------------------------------------------- piece bucketing ---
__global__ __launch_bounds__(1024)
void bucket_kernel(const float* __restrict__ xyz2, const int* __restrict__ pid2,
                   float4* __restrict__ bpts, int* __restrict__ boff)
{
    __shared__ int spid[NS];
    __shared__ int segcnt[64][NP];
    __shared__ int segbase[64][NP];
    __shared__ int poff[NP + 1];
    const int t = threadIdx.x;
    for (int i = t; i < NS; i += 1024) spid[i] = pid2[i];
    __syncthreads();
    {
        const int seg = t >> 4, p = t & 15;
        int c = 0;
        const int b = seg * 64;
        for (int i = 0; i < 64; ++i) c += (spid[b + i] == p);
        segcnt[seg][p] = c;
    }
    __syncthreads();
    if (t < NP) {
        int run = 0;
        for (int s = 0; s < 64; ++s) { segbase[s][t] = run; run += segcnt[s][t]; }
        poff[t] = run;
    }
    __syncthreads();
    if (t == 0) {
        int run = 0;
        for (int p = 0; p < NP; ++p) { int c = poff[p]; poff[p] = run; run += c; }
        poff[NP] = run;
    }
    __syncthreads();
    if (t <= NP) boff[t] = poff[t];
    {
        const int seg = t >> 4, p = t & 15;
        int pos = poff[p] + segbase[seg][p];
        const int b = seg * 64;
        for (int i = 0; i < 64; ++i) {
            const int gi = b + i;
            if (spid[gi] == p) {
                bpts[pos] = make_float4(xyz2[gi], xyz2[NS + gi], xyz2[2 * NS + gi],
                                        __int_as_float(gi));
                ++pos;
            }
        }
    }
}

// ---------------------------------------------------------------- KNN ------
#define LEXLT(d, j, e, je) ((d) < (e) || ((d) == (e) && (j) < (je)))

__global__ __launch_bounds__(256)
void knn_kernel(const float* __restrict__ xyz1, const int* __restrict__ pid1,
                const float4* __restrict__ bpts, const int* __restrict__ boff,
                int* __restrict__ oidx, float* __restrict__ ow)
{
    const int t = blockIdx.x * 256 + threadIdx.x;
    const int q = t >> 4;
    const int k = t & 15;
    const float qx = xyz1[q], qy = xyz1[NQ + q], qz = xyz1[2 * NQ + q];
    const int p = pid1[q];
    const int s0 = boff[p], s1 = boff[p + 1];

    float e0 = INFINITY, e1 = INFINITY, e2 = INFINITY;
    int j0 = 0, j1 = 0, j2 = 0;
    for (int i = s0 + k; i < s1; i += 16) {
        float4 pt = bpts[i];
        const float dx = pt.x - qx, dy = pt.y - qy, dz = pt.z - qz;
        const float d = fmaf(dx, dx, fmaf(dy, dy, dz * dz));
        const int oi = __float_as_int(pt.w);
        const bool b0 = LEXLT(d, oi, e0, j0), b1 = LEXLT(d, oi, e1, j1),
                   b2 = LEXLT(d, oi, e2, j2);
        e2 = b2 ? (b1 ? e1 : d) : e2;  j2 = b2 ? (b1 ? j1 : oi) : j2;
        e1 = b1 ? (b0 ? e0 : d) : e1;  j1 = b1 ? (b0 ? j0 : oi) : j1;
        e0 = b0 ? d : e0;              j0 = b0 ? oi : j0;
    }
    #pragma unroll
    for (int m = 1; m <= 8; m <<= 1) {
        float f[3]; int gi[3];
        f[0] = __shfl_xor(e0, m); gi[0] = __shfl_xor(j0, m);
        f[1] = __shfl_xor(e1, m); gi[1] = __shfl_xor(j1, m);
        f[2] = __shfl_xor(e2, m); gi[2] = __shfl_xor(j2, m);
        #pragma unroll
        for (int c = 0; c < 3; ++c) {
            const float d = f[c]; const int oi = gi[c];
            const bool b0 = LEXLT(d, oi, e0, j0), b1 = LEXLT(d, oi, e1, j1),
                       b2 = LEXLT(d, oi, e2, j2);
            e2 = b2 ? (b1 ? e1 : d) : e2;  j2 = b2 ? (b1 ? j1 : oi) : j2;
            e1 = b1 ? (b0 ? e0 : d) : e1;  j1 = b1 ? (b0 ? j0 : oi) : j1;
            e0 = b0 ? d : e0;              j0 = b0 ? oi : j0;
        }
    }
    if (k == 0) {
        if (isinf(e0)) { j0 = 0;  e0 = BIGD; }
        if (isinf(e1)) { j1 = j0; e1 = BIGD; }
        if (isinf(e2)) { j2 = j0; e2 = BIGD; }
        const float w0 = 1.f / (e0 + EPSW), w1 = 1.f / (e1 + EPSW), w2 = 1.f / (e2 + EPSW);
        const float inv = 1.f / (w0 + w1 + w2);
        oidx[q * 3 + 0] = j0; oidx[q * 3 + 1] = j1; oidx[q * 3 + 2] = j2;
        ow[q * 3 + 0] = w0 * inv; ow[q * 3 + 1] = w1 * inv; ow[q * 3 + 2] = w2 * inv;
    }
}

// ----------------------------------------------- weights fp32 -> bf16 ------
__global__ __launch_bounds__(256)
void cvtw_kernel(const float* __restrict__ w0, const float* __restrict__ w1,
                 unsigned short* __restrict__ o0, unsigned short* __restrict__ o1)
{
    const int i = blockIdx.x * 256 + threadIdx.x;
    const float* src; unsigned short* dst; int j;
    if (i < 32768) { src = w0; dst = o0; j = i; }
    else           { src = w1; dst = o1; j = i - 32768; }
    float4 v = ((const float4*)src)[j];
    ushort4 o;
    o.x = f2bf(v.x); o.y = f2bf(v.y); o.z = f2bf(v.z); o.w = f2bf(v.w);
    ((ushort4*)dst)[j] = o;
}

// -------------------- [C][srcN] fp32 -> dst[n][kt] bf16 (64x64 tiles) ------
__global__ __launch_bounds__(256)
void tcvt_kernel(const float* __restrict__ src, int srcN,
                 unsigned short* __restrict__ dst, int kt, int coff)
{
    __shared__ float tile[64][65];
    const int cb = blockIdx.x * 64;
    const int nb = blockIdx.y * 64;
    #pragma unroll
    for (int rnd = 0; rnd < 4; ++rnd) {
        const int r = rnd * 16 + (threadIdx.x >> 4);
        const int c4 = (threadIdx.x & 15) * 4;
        float4 v = *(const float4*)&src[(size_t)(cb + r) * srcN + nb + c4];
        tile[r][c4 + 0] = v.x; tile[r][c4 + 1] = v.y;
        tile[r][c4 + 2] = v.z; tile[r][c4 + 3] = v.w;
    }
    __syncthreads();
    #pragma unroll
    for (int half = 0; half < 2; ++half) {
        const int p  = (threadIdx.x >> 3) + half * 32;
        const int cg = threadIdx.x & 7;
        ushort4 o0, o1;
        o0.x = f2bf(tile[cg * 8 + 0][p]); o0.y = f2bf(tile[cg * 8 + 1][p]);
        o0.z = f2bf(tile[cg * 8 + 2][p]); o0.w = f2bf(tile[cg * 8 + 3][p]);
        o1.x = f2bf(tile[cg * 8 + 4][p]); o1.y = f2bf(tile[cg * 8 + 5][p]);
        o1.z = f2bf(tile[cg * 8 + 6][p]); o1.w = f2bf(tile[cg * 8 + 7][p]);
        ushort4* d = (ushort4*)&dst[(size_t)(nb + p) * kt + coff + cb + cg * 8];
        d[0] = o0; d[1] = o1;
    }
}

// ----------------------- interp fused into Xt rows (bf16) ------------------
__global__ __launch_bounds__(256)
void interp_kernel(const unsigned short* __restrict__ p2Tb,
                   const int* __restrict__ oidx, const float* __restrict__ ow,
                   unsigned short* __restrict__ Xt)
{
    const int n = (blockIdx.x * 256 + threadIdx.x) >> 6;
    const int l = threadIdx.x & 63;
    const int i0 = oidx[n * 3 + 0], i1 = oidx[n * 3 + 1], i2 = oidx[n * 3 + 2];
    const float w0 = ow[n * 3 + 0], w1 = ow[n * 3 + 1], w2 = ow[n * 3 + 2];
    ushort4 a = *(const ushort4*)&p2Tb[(size_t)i0 * 256 + l * 4];
    ushort4 b = *(const ushort4*)&p2Tb[(size_t)i1 * 256 + l * 4];
    ushort4 c = *(const ushort4*)&p2Tb[(size_t)i2 * 256 + l * 4];
    ushort4 o;
    o.x = f2bf(w0 * bf2f(a.x) + w1 * bf2f(b.x) + w2 * bf2f(c.x));
    o.y = f2bf(w0 * bf2f(a.y) + w1 * bf2f(b.y) + w2 * bf2f(c.y));
    o.z = f2bf(w0 * bf2f(a.z) + w1 * bf2f(b.z) + w2 * bf2f(c.z));
    o.w = f2bf(w0 * bf2f(a.w) + w1 * bf2f(b.w) + w2 * bf2f(c.w));
    *(ushort4*)&Xt[(size_t)n * 512 + 256 + l * 4] = o;
}

// ------------------------------------------------------------- MFMA GEMM ---
// Block tile M=128 x N=32, grid = 2 mtiles x 512 ntiles = 1024 blocks
// (4 blocks/CU, 16 waves/CU). Wave w owns M-rows [mtile*128+w*32, +32).
// Store-only epilogue (acc never leaves AGPRs except for the final convert).
template<int K, bool LOAD_DIRECT>
__global__ __launch_bounds__(256)
void mgemm_kernel(const unsigned short* __restrict__ Wb,
                  const unsigned short* __restrict__ Xsrc,
                  const float* __restrict__ sum_in, const float* __restrict__ sq_in,
                  const float* __restrict__ g, const float* __restrict__ bt,
                  unsigned short* __restrict__ Yout)
{
    constexpr int K2 = K * 2;                     // row bytes
    __shared__ unsigned char sB[32 * K2];
    const int tid = threadIdx.x;
    const int mtile = blockIdx.x & 1;
    const int n0 = (blockIdx.x >> 1) * 32;

    if constexpr (!LOAD_DIRECT) {
        // derive BN1 scale/shift, then reg-stage B applying relu(v*sc+sh)
        __shared__ float scs[256], shs[256];
        const float mean = sum_in[tid] * (1.f / NQ);
        const float var  = sq_in[tid] * (1.f / NQ) - mean * mean;
        const float rs = rsqrtf(var + 1e-5f);
        const float s = g[tid] * rs;
        scs[tid] = s; shs[tid] = bt[tid] - mean * s;
        __syncthreads();
        const int row = tid >> 3;
        const int cb0 = (tid & 7) * 64;           // byte col base
        #pragma unroll
        for (int ch = 0; ch < 4; ++ch) {
            const int cb = cb0 + ch * 16;
            const short8 v = *(const short8*)&Xsrc[(size_t)(n0 + row) * 256 + cb / 2];
            ushort4 lo, hi;
            const int c = cb / 2;
            lo.x = f2bf(fmaxf(fmaf(bf2f((unsigned short)v[0]), scs[c+0], shs[c+0]), 0.f));
            lo.y = f2bf(fmaxf(fmaf(bf2f((unsigned short)v[1]), scs[c+1], shs[c+1]), 0.f));
            lo.z = f2bf(fmaxf(fmaf(bf2f((unsigned short)v[2]), scs[c+2], shs[c+2]), 0.f));
            lo.w = f2bf(fmaxf(fmaf(bf2f((unsigned short)v[3]), scs[c+3], shs[c+3]), 0.f));
            hi.x = f2bf(fmaxf(fmaf(bf2f((unsigned short)v[4]), scs[c+4], shs[c+4]), 0.f));
            hi.y = f2bf(fmaxf(fmaf(bf2f((unsigned short)v[5]), scs[c+5], shs[c+5]), 0.f));
            hi.z = f2bf(fmaxf(fmaf(bf2f((unsigned short)v[6]), scs[c+6], shs[c+6]), 0.f));
            hi.w = f2bf(fmaxf(fmaf(bf2f((unsigned short)v[7]), scs[c+7], shs[c+7]), 0.f));
            unsigned char* d = &sB[row * K2 + (cb ^ ((row & 7) << 4))];
            ((ushort4*)d)[0] = lo; ((ushort4*)d)[1] = hi;
        }
    } else {
        constexpr int ROUNDS = (32 * K2 / 16) / 256;
        #pragma unroll
        for (int j = 0; j < ROUNDS; ++j) {
            const int p   = (j * 256 + tid) * 16;
            const int row = p >> 10;              // K==512 only
            const int c   = p & (K2 - 1);
            const int q   = c ^ ((row & 7) << 4);
            const char* gp = (const char*)(Xsrc + (size_t)(n0 + row) * K) + q;
            __builtin_amdgcn_global_load_lds(
                (const __attribute__((address_space(1))) void*)gp,
                (__attribute__((address_space(3))) void*)(sB + p), 16, 0, 0);
        }
    }
    __syncthreads();

    const int w = tid >> 6, l = tid & 63;
    const int lr = l & 15, lk = l >> 4;
    const int mbase = mtile * 128 + w * 32;
    f32x4 acc[2][2] = {};
    #pragma unroll
    for (int ks = 0; ks < K / 32; ++ks) {
        short8 b[2];
        #pragma unroll
        for (int nf = 0; nf < 2; ++nf) {
            const int r = nf * 16 + lr;
            const int cbyte = ks * 64 + lk * 16;
            b[nf] = *(const short8*)&sB[r * K2 + (cbyte ^ ((r & 7) << 4))];
        }
        #pragma unroll
        for (int mf = 0; mf < 2; ++mf) {
            const int m = mbase + mf * 16 + lr;
            const short8 a = *(const short8*)&Wb[(size_t)m * K + ks * 32 + lk * 8];
            #pragma unroll
            for (int nf = 0; nf < 2; ++nf)
                acc[mf][nf] = __builtin_amdgcn_mfma_f32_16x16x32_bf16(
                                  a, b[nf], acc[mf][nf], 0, 0, 0);
        }
    }
    #pragma unroll
    for (int mf = 0; mf < 2; ++mf)
        #pragma unroll
        for (int nf = 0; nf < 2; ++nf) {
            const int n = n0 + nf * 16 + lr;
            const int moff = mbase + mf * 16 + lk * 4;
            ushort4 o;
            o.x = f2bf(acc[mf][nf][0]); o.y = f2bf(acc[mf][nf][1]);
            o.z = f2bf(acc[mf][nf][2]); o.w = f2bf(acc[mf][nf][3]);
            *(ushort4*)&Yout[(size_t)n * 256 + moff] = o;
        }
}

// ------------------------- per-channel stats over Y [N][256] bf16 ----------
// 32 blocks x 256 thr; block handles 512 rows; LDS-reduced partials, then
// 512 low-contention global atomics per block.
__global__ __launch_bounds__(256)
void stats_kernel(const unsigned short* __restrict__ Y,
                  float* __restrict__ sum, float* __restrict__ sq)
{
    __shared__ float red[2][8][256];
    const int t = threadIdx.x;
    const int c8 = (t & 31) * 8;
    const int rsub = t >> 5;
    const int r0 = blockIdx.x * 512 + rsub;
    float s[8] = {}, q[8] = {};
    for (int i = 0; i < 64; ++i) {
        const short8 v = *(const short8*)&Y[(size_t)(r0 + i * 8) * 256 + c8];
        #pragma unroll
        for (int j = 0; j < 8; ++j) {
            const float f = bf2f((unsigned short)v[j]);
            s[j] += f; q[j] += f * f;
        }
    }
    #pragma unroll
    for (int j = 0; j < 8; ++j) {
        red[0][rsub][c8 + j] = s[j];
        red[1][rsub][c8 + j] = q[j];
    }
    __syncthreads();
    float ts = 0.f, tq = 0.f;
    #pragma unroll
    for (int r = 0; r < 8; ++r) { ts += red[0][r][t]; tq += red[1][r][t]; }
    atomicAdd(&sum[t], ts);
    atomicAdd(&sq[t], tq);
}

// --------------- final: BN2 + relu + transpose [N][256] -> out [256][NQ] ---
__global__ __launch_bounds__(256)
void bnt_kernel(const unsigned short* __restrict__ Y, const float* __restrict__ sum,
                const float* __restrict__ sq, const float* __restrict__ g,
                const float* __restrict__ bt, float* __restrict__ out)
{
    __shared__ float tile[64][65];
    __shared__ float scs[64], shs[64];
    const int t = threadIdx.x;
    const int cb = blockIdx.x * 64;
    const int nb = blockIdx.y * 64;
    if (t < 64) {
        const int c = cb + t;
        const float mean = sum[c] * (1.f / NQ);
        const float var  = sq[c] * (1.f / NQ) - mean * mean;
        const float rs = rsqrtf(var + 1e-5f);
        const float s = g[c] * rs;
        scs[t] = s; shs[t] = bt[c] - mean * s;
    }
    __syncthreads();
    #pragma unroll
    for (int rnd = 0; rnd < 4; ++rnd) {
        const int nl = rnd * 16 + (t >> 4);
        const int c4 = (t & 15) * 4;
        ushort4 v = *(const ushort4*)&Y[(size_t)(nb + nl) * 256 + cb + c4];
        tile[c4 + 0][nl] = fmaxf(fmaf(bf2f(v.x), scs[c4 + 0], shs[c4 + 0]), 0.f);
        tile[c4 + 1][nl] = fmaxf(fmaf(bf2f(v.y), scs[c4 + 1], shs[c4 + 1]), 0.f);
        tile[c4 + 2][nl] = fmaxf(fmaf(bf2f(v.z), scs[c4 + 2], shs[c4 + 2]), 0.f);
        tile[c4 + 3][nl] = fmaxf(fmaf(bf2f(v.w), scs[c4 + 3], shs[c4 + 3]), 0.f);
    }
    __syncthreads();
    const int cl = t >> 2, qq = t & 3;
    float* orow = out + (size_t)(cb + cl) * NQ + nb + qq * 16;
    #pragma unroll
    for (int k = 0; k < 4; ++k) {
        float4 v = make_float4(tile[cl][qq * 16 + k * 4 + 0], tile[cl][qq * 16 + k * 4 + 1],
                               tile[cl][qq * 16 + k * 4 + 2], tile[cl][qq * 16 + k * 4 + 3]);
        *(float4*)&orow[k * 4] = v;
    }
}

// ------------------------------------------------------------------ launch -
extern "C" void kernel_launch(void* const* d_in, const int* in_sizes, int n_in,
                              void* d_out, int out_size, void* d_ws, size_t ws_size,
                              hipStream_t stream)
{
    const float* xyz1    = (const float*)d_in[0];
    const float* xyz2    = (const float*)d_in[1];
    const int*   pid1    = (const int*)d_in[2];
    const int*   pid2    = (const int*)d_in[3];
    const float* points1 = (const float*)d_in[4];
    const float* points2 = (const float*)d_in[5];
    const float* w0      = (const float*)d_in[6];
    const float* g0      = (const float*)d_in[8];
    const float* bt0     = (const float*)d_in[9];
    const float* w1      = (const float*)d_in[10];
    const float* g1      = (const float*)d_in[12];
    const float* bt1     = (const float*)d_in[13];
    float* out = (float*)d_out;

    char* ws = (char*)d_ws;
    int*            boff  = (int*)(ws + 0);                  // 128 B
    float*          sums  = (float*)(ws + 128);              // 4 KB
    float*          sum0  = sums, *sq0 = sums + 256, *sum1 = sums + 512, *sq1 = sums + 768;
    int*            idxb  = (int*)(ws + 8192);               // 192 KB
    float*          wb    = (float*)(ws + 8192 + 196608);    // 192 KB
    unsigned short* Wb0   = (unsigned short*)(ws + 8192 + 393216);   // 256 KB
    unsigned short* Wb1   = (unsigned short*)(ws + 8192 + 655360);   // 128 KB
    float4*         bpts  = (float4*)(ws + 8192 + 786432);   // 64 KB
    unsigned short* p2Tb  = (unsigned short*)(ws + 1048576); // 2 MB
    unsigned short* Xt    = (unsigned short*)(ws + 1048576 + 2097152);            // 16 MB
    unsigned short* y0Tb  = (unsigned short*)(ws + 1048576 + 2097152 + 16777216); // 8 MB
    unsigned short* y1Tb  = (unsigned short*)(ws + 1048576 + 2097152 + 25165824); // 8 MB

    hipMemsetAsync(sums, 0, 4096, stream);
    bucket_kernel<<<1, 1024, 0, stream>>>(xyz2, pid2, bpts, boff);
    knn_kernel<<<NQ * 16 / 256, 256, 0, stream>>>(xyz1, pid1, bpts, boff, idxb, wb);
    cvtw_kernel<<<192, 256, 0, stream>>>(w0, w1, Wb0, Wb1);
    tcvt_kernel<<<dim3(4, NS / 64), 256, 0, stream>>>(points2, NS, p2Tb, 256, 0);
    tcvt_kernel<<<dim3(4, NQ / 64), 256, 0, stream>>>(points1, NQ, Xt, 512, 0);
    interp_kernel<<<NQ * 64 / 256, 256, 0, stream>>>(p2Tb, idxb, wb, Xt);
    mgemm_kernel<512, true><<<2 * (NQ / 32), 256, 0, stream>>>(
        Wb0, Xt, nullptr, nullptr, nullptr, nullptr, y0Tb);
    stats_kernel<<<32, 256, 0, stream>>>(y0Tb, sum0, sq0);
    mgemm_kernel<256, false><<<2 * (NQ / 32), 256, 0, stream>>>(
        Wb1, y0Tb, sum0, sq0, g0, bt0, y1Tb);
    stats_kernel<<<32, 256, 0, stream>>>(y1Tb, sum1, sq1);
    bnt_kernel<<<dim3(4, NQ / 64), 256, 0, stream>>>(y1Tb, sum1, sq1, g1, bt1, out);
}

// Round 6
// 200.430 us; speedup vs baseline: 1.4076x; 1.0243x over previous
//
#include <hip/hip_runtime.h>
#include <math.h>

#define NQ 16384
#define NS 4096
#define NCH 256
#define NP 16
#define BIGD 1e8f
#define EPSW 1e-8f

typedef __attribute__((ext_vector_type(8))) short short8;
typedef __attribute__((ext_vector_type(4))) float f32x4;

static __device__ __forceinline__ unsigned short f2bf(float x) {
    unsigned u = __float_as_uint(x);
    unsigned r = (u + 0x7fff + ((u >> 16) & 1)) >> 16;   // RNE
    return (unsigned short)r;
}
static __device__ __forceinline__ float bf2f(unsigned short u) {
    return __uint_as_float(((unsigned)u) << 16);
}

// ------------------------------------------------------- piece bucketing ---
__global__ __launch_bounds__(1024)
void bucket_kernel(const float* __restrict__ xyz2, const int* __restrict__ pid2,
                   float4* __restrict__ bpts, int* __restrict__ boff)
{
    __shared__ int spid[NS];
    __shared__ int segcnt[64][NP];
    __shared__ int segbase[64][NP];
    __shared__ int poff[NP + 1];
    const int t = threadIdx.x;
    for (int i = t; i < NS; i += 1024) spid[i] = pid2[i];
    __syncthreads();
    {
        const int seg = t >> 4, p = t & 15;
        int c = 0;
        const int b = seg * 64;
        for (int i = 0; i < 64; ++i) c += (spid[b + i] == p);
        segcnt[seg][p] = c;
    }
    __syncthreads();
    if (t < NP) {
        int run = 0;
        for (int s = 0; s < 64; ++s) { segbase[s][t] = run; run += segcnt[s][t]; }
        poff[t] = run;
    }
    __syncthreads();
    if (t == 0) {
        int run = 0;
        for (int p = 0; p < NP; ++p) { int c = poff[p]; poff[p] = run; run += c; }
        poff[NP] = run;
    }
    __syncthreads();
    if (t <= NP) boff[t] = poff[t];
    {
        const int seg = t >> 4, p = t & 15;
        int pos = poff[p] + segbase[seg][p];
        const int b = seg * 64;
        for (int i = 0; i < 64; ++i) {
            const int gi = b + i;
            if (spid[gi] == p) {
                bpts[pos] = make_float4(xyz2[gi], xyz2[NS + gi], xyz2[2 * NS + gi],
                                        __int_as_float(gi));
                ++pos;
            }
        }
    }
}

// ---------------------------------------------------------------- KNN ------
#define LEXLT(d, j, e, je) ((d) < (e) || ((d) == (e) && (j) < (je)))

__global__ __launch_bounds__(256)
void knn_kernel(const float* __restrict__ xyz1, const int* __restrict__ pid1,
                const float4* __restrict__ bpts, const int* __restrict__ boff,
                int* __restrict__ oidx, float* __restrict__ ow)
{
    const int t = blockIdx.x * 256 + threadIdx.x;
    const int q = t >> 4;
    const int k = t & 15;
    const float qx = xyz1[q], qy = xyz1[NQ + q], qz = xyz1[2 * NQ + q];
    const int p = pid1[q];
    const int s0 = boff[p], s1 = boff[p + 1];

    float e0 = INFINITY, e1 = INFINITY, e2 = INFINITY;
    int j0 = 0, j1 = 0, j2 = 0;
    for (int i = s0 + k; i < s1; i += 16) {
        float4 pt = bpts[i];
        const float dx = pt.x - qx, dy = pt.y - qy, dz = pt.z - qz;
        const float d = fmaf(dx, dx, fmaf(dy, dy, dz * dz));
        const int oi = __float_as_int(pt.w);
        const bool b0 = LEXLT(d, oi, e0, j0), b1 = LEXLT(d, oi, e1, j1),
                   b2 = LEXLT(d, oi, e2, j2);
        e2 = b2 ? (b1 ? e1 : d) : e2;  j2 = b2 ? (b1 ? j1 : oi) : j2;
        e1 = b1 ? (b0 ? e0 : d) : e1;  j1 = b1 ? (b0 ? j0 : oi) : j1;
        e0 = b0 ? d : e0;              j0 = b0 ? oi : j0;
    }
    #pragma unroll
    for (int m = 1; m <= 8; m <<= 1) {
        float f[3]; int gi[3];
        f[0] = __shfl_xor(e0, m); gi[0] = __shfl_xor(j0, m);
        f[1] = __shfl_xor(e1, m); gi[1] = __shfl_xor(j1, m);
        f[2] = __shfl_xor(e2, m); gi[2] = __shfl_xor(j2, m);
        #pragma unroll
        for (int c = 0; c < 3; ++c) {
            const float d = f[c]; const int oi = gi[c];
            const bool b0 = LEXLT(d, oi, e0, j0), b1 = LEXLT(d, oi, e1, j1),
                       b2 = LEXLT(d, oi, e2, j2);
            e2 = b2 ? (b1 ? e1 : d) : e2;  j2 = b2 ? (b1 ? j1 : oi) : j2;
            e1 = b1 ? (b0 ? e0 : d) : e1;  j1 = b1 ? (b0 ? j0 : oi) : j1;
            e0 = b0 ? d : e0;              j0 = b0 ? oi : j0;
        }
    }
    if (k == 0) {
        if (isinf(e0)) { j0 = 0;  e0 = BIGD; }
        if (isinf(e1)) { j1 = j0; e1 = BIGD; }
        if (isinf(e2)) { j2 = j0; e2 = BIGD; }
        const float w0 = 1.f / (e0 + EPSW), w1 = 1.f / (e1 + EPSW), w2 = 1.f / (e2 + EPSW);
        const float inv = 1.f / (w0 + w1 + w2);
        oidx[q * 3 + 0] = j0; oidx[q * 3 + 1] = j1; oidx[q * 3 + 2] = j2;
        ow[q * 3 + 0] = w0 * inv; ow[q * 3 + 1] = w1 * inv; ow[q * 3 + 2] = w2 * inv;
    }
}

// ----------------------------------------------- weights fp32 -> bf16 ------
__global__ __launch_bounds__(256)
void cvtw_kernel(const float* __restrict__ w0, const float* __restrict__ w1,
                 unsigned short* __restrict__ o0, unsigned short* __restrict__ o1)
{
    const int i = blockIdx.x * 256 + threadIdx.x;
    const float* src; unsigned short* dst; int j;
    if (i < 32768) { src = w0; dst = o0; j = i; }
    else           { src = w1; dst = o1; j = i - 32768; }
    float4 v = ((const float4*)src)[j];
    ushort4 o;
    o.x = f2bf(v.x); o.y = f2bf(v.y); o.z = f2bf(v.z); o.w = f2bf(v.w);
    ((ushort4*)dst)[j] = o;
}

// -------------------- [C][srcN] fp32 -> dst[n][kt] bf16 (64x64 tiles) ------
__global__ __launch_bounds__(256)
void tcvt_kernel(const float* __restrict__ src, int srcN,
                 unsigned short* __restrict__ dst, int kt, int coff)
{
    __shared__ float tile[64][65];
    const int cb = blockIdx.x * 64;
    const int nb = blockIdx.y * 64;
    #pragma unroll
    for (int rnd = 0; rnd < 4; ++rnd) {
        const int r = rnd * 16 + (threadIdx.x >> 4);
        const int c4 = (threadIdx.x & 15) * 4;
        float4 v = *(const float4*)&src[(size_t)(cb + r) * srcN + nb + c4];
        tile[r][c4 + 0] = v.x; tile[r][c4 + 1] = v.y;
        tile[r][c4 + 2] = v.z; tile[r][c4 + 3] = v.w;
    }
    __syncthreads();
    #pragma unroll
    for (int half = 0; half < 2; ++half) {
        const int p  = (threadIdx.x >> 3) + half * 32;
        const int cg = threadIdx.x & 7;
        ushort4 o0, o1;
        o0.x = f2bf(tile[cg * 8 + 0][p]); o0.y = f2bf(tile[cg * 8 + 1][p]);
        o0.z = f2bf(tile[cg * 8 + 2][p]); o0.w = f2bf(tile[cg * 8 + 3][p]);
        o1.x = f2bf(tile[cg * 8 + 4][p]); o1.y = f2bf(tile[cg * 8 + 5][p]);
        o1.z = f2bf(tile[cg * 8 + 6][p]); o1.w = f2bf(tile[cg * 8 + 7][p]);
        ushort4* d = (ushort4*)&dst[(size_t)(nb + p) * kt + coff + cb + cg * 8];
        d[0] = o0; d[1] = o1;
    }
}

// ----------------------- interp fused into Xt rows (bf16) ------------------
__global__ __launch_bounds__(256)
void interp_kernel(const unsigned short* __restrict__ p2Tb,
                   const int* __restrict__ oidx, const float* __restrict__ ow,
                   unsigned short* __restrict__ Xt)
{
    const int n = (blockIdx.x * 256 + threadIdx.x) >> 6;
    const int l = threadIdx.x & 63;
    const int i0 = oidx[n * 3 + 0], i1 = oidx[n * 3 + 1], i2 = oidx[n * 3 + 2];
    const float w0 = ow[n * 3 + 0], w1 = ow[n * 3 + 1], w2 = ow[n * 3 + 2];
    ushort4 a = *(const ushort4*)&p2Tb[(size_t)i0 * 256 + l * 4];
    ushort4 b = *(const ushort4*)&p2Tb[(size_t)i1 * 256 + l * 4];
    ushort4 c = *(const ushort4*)&p2Tb[(size_t)i2 * 256 + l * 4];
    ushort4 o;
    o.x = f2bf(w0 * bf2f(a.x) + w1 * bf2f(b.x) + w2 * bf2f(c.x));
    o.y = f2bf(w0 * bf2f(a.y) + w1 * bf2f(b.y) + w2 * bf2f(c.y));
    o.z = f2bf(w0 * bf2f(a.z) + w1 * bf2f(b.z) + w2 * bf2f(c.z));
    o.w = f2bf(w0 * bf2f(a.w) + w1 * bf2f(b.w) + w2 * bf2f(c.w));
    *(ushort4*)&Xt[(size_t)n * 512 + 256 + l * 4] = o;
}

// ------------------------------------------------------------- MFMA GEMM ---
// Block = full M=256 x N=32 (one 32-point slab staged ONCE), 512 threads,
// 8 waves each owning 32 M-rows (acc 2x2 fragments). Grid = NQ/32 = 512
// blocks -> 2 blocks/CU, 16 waves/CU. Store-only epilogue.
template<int K, bool LOAD_DIRECT>
__global__ __launch_bounds__(512)
void mgemm_kernel(const unsigned short* __restrict__ Wb,
                  const unsigned short* __restrict__ Xsrc,
                  const float* __restrict__ sum_in, const float* __restrict__ sq_in,
                  const float* __restrict__ g, const float* __restrict__ bt,
                  unsigned short* __restrict__ Yout)
{
    constexpr int K2 = K * 2;                     // row bytes
    __shared__ unsigned char sB[32 * K2];
    const int tid = threadIdx.x;
    const int n0 = blockIdx.x * 32;

    if constexpr (!LOAD_DIRECT) {
        // derive BN1 scale/shift, then reg-stage B applying relu(v*sc+sh)
        __shared__ float scs[256], shs[256];
        if (tid < 256) {
            const float mean = sum_in[tid] * (1.f / NQ);
            const float var  = sq_in[tid] * (1.f / NQ) - mean * mean;
            const float rs = rsqrtf(var + 1e-5f);
            const float s = g[tid] * rs;
            scs[tid] = s; shs[tid] = bt[tid] - mean * s;
        }
        __syncthreads();
        const int row = tid >> 4;                 // 0..31
        #pragma unroll
        for (int ch = 0; ch < 2; ++ch) {
            const int cb = (tid & 15) * 32 + ch * 16;   // byte col base
            const int c = cb / 2;                        // channel base
            const short8 v = *(const short8*)&Xsrc[(size_t)(n0 + row) * 256 + c];
            ushort4 lo, hi;
            lo.x = f2bf(fmaxf(fmaf(bf2f((unsigned short)v[0]), scs[c+0], shs[c+0]), 0.f));
            lo.y = f2bf(fmaxf(fmaf(bf2f((unsigned short)v[1]), scs[c+1], shs[c+1]), 0.f));
            lo.z = f2bf(fmaxf(fmaf(bf2f((unsigned short)v[2]), scs[c+2], shs[c+2]), 0.f));
            lo.w = f2bf(fmaxf(fmaf(bf2f((unsigned short)v[3]), scs[c+3], shs[c+3]), 0.f));
            hi.x = f2bf(fmaxf(fmaf(bf2f((unsigned short)v[4]), scs[c+4], shs[c+4]), 0.f));
            hi.y = f2bf(fmaxf(fmaf(bf2f((unsigned short)v[5]), scs[c+5], shs[c+5]), 0.f));
            hi.z = f2bf(fmaxf(fmaf(bf2f((unsigned short)v[6]), scs[c+6], shs[c+6]), 0.f));
            hi.w = f2bf(fmaxf(fmaf(bf2f((unsigned short)v[7]), scs[c+7], shs[c+7]), 0.f));
            unsigned char* d = &sB[row * K2 + (cb ^ ((row & 7) << 4))];
            ((ushort4*)d)[0] = lo; ((ushort4*)d)[1] = hi;
        }
    } else {
        constexpr int ROUNDS = (32 * K2 / 16) / 512;    // K=512: 4
        #pragma unroll
        for (int j = 0; j < ROUNDS; ++j) {
            const int p   = (j * 512 + tid) * 16;
            const int row = p >> 10;              // K2==1024 (K=512 only)
            const int c   = p & (K2 - 1);
            const int q   = c ^ ((row & 7) << 4);
            const char* gp = (const char*)(Xsrc + (size_t)(n0 + row) * K) + q;
            __builtin_amdgcn_global_load_lds(
                (const __attribute__((address_space(1))) void*)gp,
                (__attribute__((address_space(3))) void*)(sB + p), 16, 0, 0);
        }
    }
    __syncthreads();

    const int w = tid >> 6, l = tid & 63;         // 8 waves
    const int lr = l & 15, lk = l >> 4;
    const int mbase = w * 32;
    f32x4 acc[2][2] = {};
    #pragma unroll
    for (int ks = 0; ks < K / 32; ++ks) {
        short8 b[2];
        #pragma unroll
        for (int nf = 0; nf < 2; ++nf) {
            const int r = nf * 16 + lr;
            const int cbyte = ks * 64 + lk * 16;
            b[nf] = *(const short8*)&sB[r * K2 + (cbyte ^ ((r & 7) << 4))];
        }
        #pragma unroll
        for (int mf = 0; mf < 2; ++mf) {
            const int m = mbase + mf * 16 + lr;
            const short8 a = *(const short8*)&Wb[(size_t)m * K + ks * 32 + lk * 8];
            #pragma unroll
            for (int nf = 0; nf < 2; ++nf)
                acc[mf][nf] = __builtin_amdgcn_mfma_f32_16x16x32_bf16(
                                  a, b[nf], acc[mf][nf], 0, 0, 0);
        }
    }
    #pragma unroll
    for (int mf = 0; mf < 2; ++mf)
        #pragma unroll
        for (int nf = 0; nf < 2; ++nf) {
            const int n = n0 + nf * 16 + lr;
            const int moff = mbase + mf * 16 + lk * 4;
            ushort4 o;
            o.x = f2bf(acc[mf][nf][0]); o.y = f2bf(acc[mf][nf][1]);
            o.z = f2bf(acc[mf][nf][2]); o.w = f2bf(acc[mf][nf][3]);
            *(ushort4*)&Yout[(size_t)n * 256 + moff] = o;
        }
}

// ------------------------- per-channel stats over Y [N][256] bf16 ----------
__global__ __launch_bounds__(256)
void stats_kernel(const unsigned short* __restrict__ Y,
                  float* __restrict__ sum, float* __restrict__ sq)
{
    __shared__ float red[2][8][256];
    const int t = threadIdx.x;
    const int c8 = (t & 31) * 8;
    const int rsub = t >> 5;
    const int r0 = blockIdx.x * 512 + rsub;
    float s[8] = {}, q[8] = {};
    for (int i = 0; i < 64; ++i) {
        const short8 v = *(const short8*)&Y[(size_t)(r0 + i * 8) * 256 + c8];
        #pragma unroll
        for (int j = 0; j < 8; ++j) {
            const float f = bf2f((unsigned short)v[j]);
            s[j] += f; q[j] += f * f;
        }
    }
    #pragma unroll
    for (int j = 0; j < 8; ++j) {
        red[0][rsub][c8 + j] = s[j];
        red[1][rsub][c8 + j] = q[j];
    }
    __syncthreads();
    float ts = 0.f, tq = 0.f;
    #pragma unroll
    for (int r = 0; r < 8; ++r) { ts += red[0][r][t]; tq += red[1][r][t]; }
    atomicAdd(&sum[t], ts);
    atomicAdd(&sq[t], tq);
}

// --------------- final: BN2 + relu + transpose [N][256] -> out [256][NQ] ---
__global__ __launch_bounds__(256)
void bnt_kernel(const unsigned short* __restrict__ Y, const float* __restrict__ sum,
                const float* __restrict__ sq, const float* __restrict__ g,
                const float* __restrict__ bt, float* __restrict__ out)
{
    __shared__ float tile[64][65];
    __shared__ float scs[64], shs[64];
    const int t = threadIdx.x;
    const int cb = blockIdx.x * 64;
    const int nb = blockIdx.y * 64;
    if (t < 64) {
        const int c = cb + t;
        const float mean = sum[c] * (1.f / NQ);
        const float var  = sq[c] * (1.f / NQ) - mean * mean;
        const float rs = rsqrtf(var + 1e-5f);
        const float s = g[c] * rs;
        scs[t] = s; shs[t] = bt[c] - mean * s;
    }
    __syncthreads();
    #pragma unroll
    for (int rnd = 0; rnd < 4; ++rnd) {
        const int nl = rnd * 16 + (t >> 4);
        const int c4 = (t & 15) * 4;
        ushort4 v = *(const ushort4*)&Y[(size_t)(nb + nl) * 256 + cb + c4];
        tile[c4 + 0][nl] = fmaxf(fmaf(bf2f(v.x), scs[c4 + 0], shs[c4 + 0]), 0.f);
        tile[c4 + 1][nl] = fmaxf(fmaf(bf2f(v.y), scs[c4 + 1], shs[c4 + 1]), 0.f);
        tile[c4 + 2][nl] = fmaxf(fmaf(bf2f(v.z), scs[c4 + 2], shs[c4 + 2]), 0.f);
        tile[c4 + 3][nl] = fmaxf(fmaf(bf2f(v.w), scs[c4 + 3], shs[c4 + 3]), 0.f);
    }
    __syncthreads();
    const int cl = t >> 2, qq = t & 3;
    float* orow = out + (size_t)(cb + cl) * NQ + nb + qq * 16;
    #pragma unroll
    for (int k = 0; k < 4; ++k) {
        float4 v = make_float4(tile[cl][qq * 16 + k * 4 + 0], tile[cl][qq * 16 + k * 4 + 1],
                               tile[cl][qq * 16 + k * 4 + 2], tile[cl][qq * 16 + k * 4 + 3]);
        *(float4*)&orow[k * 4] = v;
    }
}

// ------------------------------------------------------------------ launch -
extern "C" void kernel_launch(void* const* d_in, const int* in_sizes, int n_in,
                              void* d_out, int out_size, void* d_ws, size_t ws_size,
                              hipStream_t stream)
{
    const float* xyz1    = (const float*)d_in[0];
    const float* xyz2    = (const float*)d_in[1];
    const int*   pid1    = (const int*)d_in[2];
    const int*   pid2    = (const int*)d_in[3];
    const float* points1 = (const float*)d_in[4];
    const float* points2 = (const float*)d_in[5];
    const float* w0      = (const float*)d_in[6];
    const float* g0      = (const float*)d_in[8];
    const float* bt0     = (const float*)d_in[9];
    const float* w1      = (const float*)d_in[10];
    const float* g1      = (const float*)d_in[12];
    const float* bt1     = (const float*)d_in[13];
    float* out = (float*)d_out;

    char* ws = (char*)d_ws;
    int*            boff  = (int*)(ws + 0);                  // 128 B
    float*          sums  = (float*)(ws + 128);              // 4 KB
    float*          sum0  = sums, *sq0 = sums + 256, *sum1 = sums + 512, *sq1 = sums + 768;
    int*            idxb  = (int*)(ws + 8192);               // 192 KB
    float*          wb    = (float*)(ws + 8192 + 196608);    // 192 KB
    unsigned short* Wb0   = (unsigned short*)(ws + 8192 + 393216);   // 256 KB
    unsigned short* Wb1   = (unsigned short*)(ws + 8192 + 655360);   // 128 KB
    float4*         bpts  = (float4*)(ws + 8192 + 786432);   // 64 KB
    unsigned short* p2Tb  = (unsigned short*)(ws + 1048576); // 2 MB
    unsigned short* Xt    = (unsigned short*)(ws + 1048576 + 2097152);            // 16 MB
    unsigned short* y0Tb  = (unsigned short*)(ws + 1048576 + 2097152 + 16777216); // 8 MB
    unsigned short* y1Tb  = (unsigned short*)(ws + 1048576 + 2097152 + 25165824); // 8 MB

    hipMemsetAsync(sums, 0, 4096, stream);
    bucket_kernel<<<1, 1024, 0, stream>>>(xyz2, pid2, bpts, boff);
    knn_kernel<<<NQ * 16 / 256, 256, 0, stream>>>(xyz1, pid1, bpts, boff, idxb, wb);
    cvtw_kernel<<<192, 256, 0, stream>>>(w0, w1, Wb0, Wb1);
    tcvt_kernel<<<dim3(4, NS / 64), 256, 0, stream>>>(points2, NS, p2Tb, 256, 0);
    tcvt_kernel<<<dim3(4, NQ / 64), 256, 0, stream>>>(points1, NQ, Xt, 512, 0);
    interp_kernel<<<NQ * 64 / 256, 256, 0, stream>>>(p2Tb, idxb, wb, Xt);
    mgemm_kernel<512, true><<<NQ / 32, 512, 0, stream>>>(
        Wb0, Xt, nullptr, nullptr, nullptr, nullptr, y0Tb);
    stats_kernel<<<32, 256, 0, stream>>>(y0Tb, sum0, sq0);
    mgemm_kernel<256, false><<<NQ / 32, 512, 0, stream>>>(
        Wb1, y0Tb, sum0, sq0, g0, bt0, y1Tb);
    stats_kernel<<<32, 256, 0, stream>>>(y1Tb, sum1, sq1);
    bnt_kernel<<<dim3(4, NQ / 64), 256, 0, stream>>>(y1Tb, sum1, sq1, g1, bt1, out);
}

// Round 7
// 176.471 us; speedup vs baseline: 1.5987x; 1.1358x over previous
//
#include <hip/hip_runtime.h>
#include <math.h>

#define NQ 16384
#define NS 4096
#define NCH 256
#define NP 16
#define BIGD 1e8f
#define EPSW 1e-8f

typedef __attribute__((ext_vector_type(8))) short short8;
typedef __attribute__((ext_vector_type(4))) float f32x4;

static __device__ __forceinline__ unsigned short f2bf(float x) {
    unsigned u = __float_as_uint(x);
    unsigned r = (u + 0x7fff + ((u >> 16) & 1)) >> 16;   // RNE
    return (unsigned short)r;
}
static __device__ __forceinline__ float bf2f(unsigned short u) {
    return __uint_as_float(((unsigned)u) << 16);
}

// ------------------------------------------------------- piece bucketing ---
// Also zeroes the 1024-float stats block (replaces a hipMemsetAsync).
__global__ __launch_bounds__(1024)
void bucket_kernel(const float* __restrict__ xyz2, const int* __restrict__ pid2,
                   float4* __restrict__ bpts, int* __restrict__ boff,
                   float* __restrict__ sums)
{
    __shared__ int spid[NS];
    __shared__ int segcnt[64][NP];
    __shared__ int segbase[64][NP];
    __shared__ int poff[NP + 1];
    const int t = threadIdx.x;
    sums[t] = 0.f;                       // sum0,sq0,sum1,sq1 (4 x 256)
    for (int i = t; i < NS; i += 1024) spid[i] = pid2[i];
    __syncthreads();
    {
        const int seg = t >> 4, p = t & 15;
        int c = 0;
        const int b = seg * 64;
        for (int i = 0; i < 64; ++i) c += (spid[b + i] == p);
        segcnt[seg][p] = c;
    }
    __syncthreads();
    if (t < NP) {
        int run = 0;
        for (int s = 0; s < 64; ++s) { segbase[s][t] = run; run += segcnt[s][t]; }
        poff[t] = run;
    }
    __syncthreads();
    if (t == 0) {
        int run = 0;
        for (int p = 0; p < NP; ++p) { int c = poff[p]; poff[p] = run; run += c; }
        poff[NP] = run;
    }
    __syncthreads();
    if (t <= NP) boff[t] = poff[t];
    {
        const int seg = t >> 4, p = t & 15;
        int pos = poff[p] + segbase[seg][p];
        const int b = seg * 64;
        for (int i = 0; i < 64; ++i) {
            const int gi = b + i;
            if (spid[gi] == p) {
                bpts[pos] = make_float4(xyz2[gi], xyz2[NS + gi], xyz2[2 * NS + gi],
                                        __int_as_float(gi));
                ++pos;
            }
        }
    }
}

// ---------------------------------------------------------------- KNN ------
#define LEXLT(d, j, e, je) ((d) < (e) || ((d) == (e) && (j) < (je)))

__global__ __launch_bounds__(256)
void knn_kernel(const float* __restrict__ xyz1, const int* __restrict__ pid1,
                const float4* __restrict__ bpts, const int* __restrict__ boff,
                int* __restrict__ oidx, float* __restrict__ ow)
{
    const int t = blockIdx.x * 256 + threadIdx.x;
    const int q = t >> 4;
    const int k = t & 15;
    const float qx = xyz1[q], qy = xyz1[NQ + q], qz = xyz1[2 * NQ + q];
    const int p = pid1[q];
    const int s0 = boff[p], s1 = boff[p + 1];

    float e0 = INFINITY, e1 = INFINITY, e2 = INFINITY;
    int j0 = 0, j1 = 0, j2 = 0;
    for (int i = s0 + k; i < s1; i += 16) {
        float4 pt = bpts[i];
        const float dx = pt.x - qx, dy = pt.y - qy, dz = pt.z - qz;
        const float d = fmaf(dx, dx, fmaf(dy, dy, dz * dz));
        const int oi = __float_as_int(pt.w);
        const bool b0 = LEXLT(d, oi, e0, j0), b1 = LEXLT(d, oi, e1, j1),
                   b2 = LEXLT(d, oi, e2, j2);
        e2 = b2 ? (b1 ? e1 : d) : e2;  j2 = b2 ? (b1 ? j1 : oi) : j2;
        e1 = b1 ? (b0 ? e0 : d) : e1;  j1 = b1 ? (b0 ? j0 : oi) : j1;
        e0 = b0 ? d : e0;              j0 = b0 ? oi : j0;
    }
    #pragma unroll
    for (int m = 1; m <= 8; m <<= 1) {
        float f[3]; int gi[3];
        f[0] = __shfl_xor(e0, m); gi[0] = __shfl_xor(j0, m);
        f[1] = __shfl_xor(e1, m); gi[1] = __shfl_xor(j1, m);
        f[2] = __shfl_xor(e2, m); gi[2] = __shfl_xor(j2, m);
        #pragma unroll
        for (int c = 0; c < 3; ++c) {
            const float d = f[c]; const int oi = gi[c];
            const bool b0 = LEXLT(d, oi, e0, j0), b1 = LEXLT(d, oi, e1, j1),
                       b2 = LEXLT(d, oi, e2, j2);
            e2 = b2 ? (b1 ? e1 : d) : e2;  j2 = b2 ? (b1 ? j1 : oi) : j2;
            e1 = b1 ? (b0 ? e0 : d) : e1;  j1 = b1 ? (b0 ? j0 : oi) : j1;
            e0 = b0 ? d : e0;              j0 = b0 ? oi : j0;
        }
    }
    if (k == 0) {
        if (isinf(e0)) { j0 = 0;  e0 = BIGD; }
        if (isinf(e1)) { j1 = j0; e1 = BIGD; }
        if (isinf(e2)) { j2 = j0; e2 = BIGD; }
        const float w0 = 1.f / (e0 + EPSW), w1 = 1.f / (e1 + EPSW), w2 = 1.f / (e2 + EPSW);
        const float inv = 1.f / (w0 + w1 + w2);
        oidx[q * 3 + 0] = j0; oidx[q * 3 + 1] = j1; oidx[q * 3 + 2] = j2;
        ow[q * 3 + 0] = w0 * inv; ow[q * 3 + 1] = w1 * inv; ow[q * 3 + 2] = w2 * inv;
    }
}

// ----------------------------------------- prep: tcvt x2 + W re-layout -----
// Transpose+convert body: src [C][srcN] fp32 -> dst[n][kt] bf16, 64x64 tile.
static __device__ __forceinline__
void tcvt_body(const float* __restrict__ src, int srcN,
               unsigned short* __restrict__ dst, int kt,
               int cb, int nb, float (*tile)[65])
{
    const int t = threadIdx.x;
    #pragma unroll
    for (int rnd = 0; rnd < 4; ++rnd) {
        const int r = rnd * 16 + (t >> 4);
        const int c4 = (t & 15) * 4;
        float4 v = *(const float4*)&src[(size_t)(cb + r) * srcN + nb + c4];
        tile[r][c4 + 0] = v.x; tile[r][c4 + 1] = v.y;
        tile[r][c4 + 2] = v.z; tile[r][c4 + 3] = v.w;
    }
    __syncthreads();
    #pragma unroll
    for (int half = 0; half < 2; ++half) {
        const int p  = (t >> 3) + half * 32;
        const int cg = t & 7;
        ushort4 o0, o1;
        o0.x = f2bf(tile[cg * 8 + 0][p]); o0.y = f2bf(tile[cg * 8 + 1][p]);
        o0.z = f2bf(tile[cg * 8 + 2][p]); o0.w = f2bf(tile[cg * 8 + 3][p]);
        o1.x = f2bf(tile[cg * 8 + 4][p]); o1.y = f2bf(tile[cg * 8 + 5][p]);
        o1.z = f2bf(tile[cg * 8 + 6][p]); o1.w = f2bf(tile[cg * 8 + 7][p]);
        ushort4* d = (ushort4*)&dst[(size_t)(nb + p) * kt + cb + cg * 8];
        d[0] = o0; d[1] = o1;
    }
}

// Weight re-layout into MFMA-fragment order:
// Wf[((g*(K/32)+ks)*64 + l)*8 + e] = W[g*16 + (l&15)][ks*32 + (l>>4)*8 + e]
// so each A-fragment load in mgemm is one contiguous 1KB segment.
static __device__ __forceinline__
void wrelay_body(const float* __restrict__ src, unsigned short* __restrict__ dst,
                 int K, int kslog, int o4)
{
    const int e4 = o4 & 1;
    const int tmp = o4 >> 1;
    const int l = tmp & 63;
    const int gks = tmp >> 6;
    const int ks = gks & ((1 << kslog) - 1);
    const int g  = gks >> kslog;
    const int row = g * 16 + (l & 15);
    const int col = ks * 32 + (l >> 4) * 8 + e4 * 4;
    float4 v = *(const float4*)&src[(size_t)row * K + col];
    ushort4 o;
    o.x = f2bf(v.x); o.y = f2bf(v.y); o.z = f2bf(v.z); o.w = f2bf(v.w);
    ((ushort4*)dst)[o4] = o;
}

__global__ __launch_bounds__(256)
void prep_kernel(const float* __restrict__ points1, const float* __restrict__ points2,
                 const float* __restrict__ w0, const float* __restrict__ w1,
                 unsigned short* __restrict__ Xt, unsigned short* __restrict__ p2Tb,
                 unsigned short* __restrict__ Wf0, unsigned short* __restrict__ Wf1)
{
    __shared__ float tile[64][65];
    const int b = blockIdx.x;
    if (b < 1024) {
        tcvt_body(points1, NQ, Xt, 512, (b & 3) * 64, (b >> 2) * 64, tile);
    } else if (b < 1280) {
        const int bb = b - 1024;
        tcvt_body(points2, NS, p2Tb, 256, (bb & 3) * 64, (bb >> 2) * 64, tile);
    } else if (b < 1408) {
        wrelay_body(w0, Wf0, 512, 4, (b - 1280) * 256 + threadIdx.x);
    } else {
        wrelay_body(w1, Wf1, 256, 3, (b - 1408) * 256 + threadIdx.x);
    }
}

// ----------------------- interp fused into Xt rows (bf16) ------------------
__global__ __launch_bounds__(256)
void interp_kernel(const unsigned short* __restrict__ p2Tb,
                   const int* __restrict__ oidx, const float* __restrict__ ow,
                   unsigned short* __restrict__ Xt)
{
    const int n = (blockIdx.x * 256 + threadIdx.x) >> 6;
    const int l = threadIdx.x & 63;
    const int i0 = oidx[n * 3 + 0], i1 = oidx[n * 3 + 1], i2 = oidx[n * 3 + 2];
    const float w0 = ow[n * 3 + 0], w1 = ow[n * 3 + 1], w2 = ow[n * 3 + 2];
    ushort4 a = *(const ushort4*)&p2Tb[(size_t)i0 * 256 + l * 4];
    ushort4 b = *(const ushort4*)&p2Tb[(size_t)i1 * 256 + l * 4];
    ushort4 c = *(const ushort4*)&p2Tb[(size_t)i2 * 256 + l * 4];
    ushort4 o;
    o.x = f2bf(w0 * bf2f(a.x) + w1 * bf2f(b.x) + w2 * bf2f(c.x));
    o.y = f2bf(w0 * bf2f(a.y) + w1 * bf2f(b.y) + w2 * bf2f(c.y));
    o.z = f2bf(w0 * bf2f(a.z) + w1 * bf2f(b.z) + w2 * bf2f(c.z));
    o.w = f2bf(w0 * bf2f(a.w) + w1 * bf2f(b.w) + w2 * bf2f(c.w));
    *(ushort4*)&Xt[(size_t)n * 512 + 256 + l * 4] = o;
}

// ------------------------------------------------------------- MFMA GEMM ---
// Block = full M=256 x N=32 (one 32-point slab staged ONCE), 512 threads,
// 8 waves each owning 32 M-rows. A from Wf (fragment-order, coalesced 1KB
// loads). Store-only epilogue.
template<int K, bool LOAD_DIRECT>
__global__ __launch_bounds__(512)
void mgemm_kernel(const unsigned short* __restrict__ Wf,
                  const unsigned short* __restrict__ Xsrc,
                  const float* __restrict__ sum_in, const float* __restrict__ sq_in,
                  const float* __restrict__ g, const float* __restrict__ bt,
                  unsigned short* __restrict__ Yout)
{
    constexpr int K2 = K * 2;                     // row bytes
    constexpr int KS = K / 32;
    __shared__ unsigned char sB[32 * K2];
    const int tid = threadIdx.x;
    const int n0 = blockIdx.x * 32;

    if constexpr (!LOAD_DIRECT) {
        // derive BN1 scale/shift, then reg-stage B applying relu(v*sc+sh)
        __shared__ float scs[256], shs[256];
        if (tid < 256) {
            const float mean = sum_in[tid] * (1.f / NQ);
            const float var  = sq_in[tid] * (1.f / NQ) - mean * mean;
            const float rs = rsqrtf(var + 1e-5f);
            const float s = g[tid] * rs;
            scs[tid] = s; shs[tid] = bt[tid] - mean * s;
        }
        __syncthreads();
        const int row = tid >> 4;                 // 0..31
        #pragma unroll
        for (int ch = 0; ch < 2; ++ch) {
            const int cb = (tid & 15) * 32 + ch * 16;   // byte col base
            const int c = cb / 2;                        // channel base (mult of 8)
            const short8 v = *(const short8*)&Xsrc[(size_t)(n0 + row) * 256 + c];
            const float4 s0 = *(const float4*)&scs[c],     s1 = *(const float4*)&scs[c + 4];
            const float4 h0 = *(const float4*)&shs[c],     h1 = *(const float4*)&shs[c + 4];
            ushort4 lo, hi;
            lo.x = f2bf(fmaxf(fmaf(bf2f((unsigned short)v[0]), s0.x, h0.x), 0.f));
            lo.y = f2bf(fmaxf(fmaf(bf2f((unsigned short)v[1]), s0.y, h0.y), 0.f));
            lo.z = f2bf(fmaxf(fmaf(bf2f((unsigned short)v[2]), s0.z, h0.z), 0.f));
            lo.w = f2bf(fmaxf(fmaf(bf2f((unsigned short)v[3]), s0.w, h0.w), 0.f));
            hi.x = f2bf(fmaxf(fmaf(bf2f((unsigned short)v[4]), s1.x, h1.x), 0.f));
            hi.y = f2bf(fmaxf(fmaf(bf2f((unsigned short)v[5]), s1.y, h1.y), 0.f));
            hi.z = f2bf(fmaxf(fmaf(bf2f((unsigned short)v[6]), s1.z, h1.z), 0.f));
            hi.w = f2bf(fmaxf(fmaf(bf2f((unsigned short)v[7]), s1.w, h1.w), 0.f));
            unsigned char* d = &sB[row * K2 + (cb ^ ((row & 7) << 4))];
            ((ushort4*)d)[0] = lo; ((ushort4*)d)[1] = hi;
        }
    } else {
        constexpr int ROUNDS = (32 * K2 / 16) / 512;    // K=512: 4
        #pragma unroll
        for (int j = 0; j < ROUNDS; ++j) {
            const int p   = (j * 512 + tid) * 16;
            const int row = p >> 10;              // K2==1024 (K=512 only)
            const int c   = p & (K2 - 1);
            const int q   = c ^ ((row & 7) << 4);
            const char* gp = (const char*)(Xsrc + (size_t)(n0 + row) * K) + q;
            __builtin_amdgcn_global_load_lds(
                (const __attribute__((address_space(1))) void*)gp,
                (__attribute__((address_space(3))) void*)(sB + p), 16, 0, 0);
        }
    }
    __syncthreads();

    const int w = tid >> 6, l = tid & 63;         // 8 waves
    const int lr = l & 15, lk = l >> 4;
    f32x4 acc[2][2] = {};
    #pragma unroll
    for (int ks = 0; ks < KS; ++ks) {
        short8 b[2];
        #pragma unroll
        for (int nf = 0; nf < 2; ++nf) {
            const int r = nf * 16 + lr;
            const int cbyte = ks * 64 + lk * 16;
            b[nf] = *(const short8*)&sB[r * K2 + (cbyte ^ ((r & 7) << 4))];
        }
        #pragma unroll
        for (int mf = 0; mf < 2; ++mf) {
            const short8 a = *(const short8*)(
                Wf + (((size_t)(w * 2 + mf) * KS + ks) * 64 + l) * 8);
            #pragma unroll
            for (int nf = 0; nf < 2; ++nf)
                acc[mf][nf] = __builtin_amdgcn_mfma_f32_16x16x32_bf16(
                                  a, b[nf], acc[mf][nf], 0, 0, 0);
        }
    }
    #pragma unroll
    for (int mf = 0; mf < 2; ++mf)
        #pragma unroll
        for (int nf = 0; nf < 2; ++nf) {
            const int n = n0 + nf * 16 + lr;
            const int moff = w * 32 + mf * 16 + lk * 4;
            ushort4 o;
            o.x = f2bf(acc[mf][nf][0]); o.y = f2bf(acc[mf][nf][1]);
            o.z = f2bf(acc[mf][nf][2]); o.w = f2bf(acc[mf][nf][3]);
            *(ushort4*)&Yout[(size_t)n * 256 + moff] = o;
        }
}

// ------------------------- per-channel stats over Y [N][256] bf16 ----------
// 64 blocks x 256 thr; block handles 256 rows; LDS partials, 512 atomics/blk.
__global__ __launch_bounds__(256)
void stats_kernel(const unsigned short* __restrict__ Y,
                  float* __restrict__ sum, float* __restrict__ sq)
{
    __shared__ float red[2][8][256];
    const int t = threadIdx.x;
    const int c8 = (t & 31) * 8;
    const int rsub = t >> 5;
    const int r0 = blockIdx.x * 256 + rsub;
    float s[8] = {}, q[8] = {};
    for (int i = 0; i < 32; ++i) {
        const short8 v = *(const short8*)&Y[(size_t)(r0 + i * 8) * 256 + c8];
        #pragma unroll
        for (int j = 0; j < 8; ++j) {
            const float f = bf2f((unsigned short)v[j]);
            s[j] += f; q[j] += f * f;
        }
    }
    #pragma unroll
    for (int j = 0; j < 8; ++j) {
        red[0][rsub][c8 + j] = s[j];
        red[1][rsub][c8 + j] = q[j];
    }
    __syncthreads();
    float ts = 0.f, tq = 0.f;
    #pragma unroll
    for (int r = 0; r < 8; ++r) { ts += red[0][r][t]; tq += red[1][r][t]; }
    atomicAdd(&sum[t], ts);
    atomicAdd(&sq[t], tq);
}

// --------------- final: BN2 + relu + transpose [N][256] -> out [256][NQ] ---
__global__ __launch_bounds__(256)
void bnt_kernel(const unsigned short* __restrict__ Y, const float* __restrict__ sum,
                const float* __restrict__ sq, const float* __restrict__ g,
                const float* __restrict__ bt, float* __restrict__ out)
{
    __shared__ float tile[64][65];
    __shared__ float scs[64], shs[64];
    const int t = threadIdx.x;
    const int cb = blockIdx.x * 64;
    const int nb = blockIdx.y * 64;
    if (t < 64) {
        const int c = cb + t;
        const float mean = sum[c] * (1.f / NQ);
        const float var  = sq[c] * (1.f / NQ) - mean * mean;
        const float rs = rsqrtf(var + 1e-5f);
        const float s = g[c] * rs;
        scs[t] = s; shs[t] = bt[c] - mean * s;
    }
    __syncthreads();
    #pragma unroll
    for (int rnd = 0; rnd < 4; ++rnd) {
        const int nl = rnd * 16 + (t >> 4);
        const int c4 = (t & 15) * 4;
        ushort4 v = *(const ushort4*)&Y[(size_t)(nb + nl) * 256 + cb + c4];
        tile[c4 + 0][nl] = fmaxf(fmaf(bf2f(v.x), scs[c4 + 0], shs[c4 + 0]), 0.f);
        tile[c4 + 1][nl] = fmaxf(fmaf(bf2f(v.y), scs[c4 + 1], shs[c4 + 1]), 0.f);
        tile[c4 + 2][nl] = fmaxf(fmaf(bf2f(v.z), scs[c4 + 2], shs[c4 + 2]), 0.f);
        tile[c4 + 3][nl] = fmaxf(fmaf(bf2f(v.w), scs[c4 + 3], shs[c4 + 3]), 0.f);
    }
    __syncthreads();
    const int cl = t >> 2, qq = t & 3;
    float* orow = out + (size_t)(cb + cl) * NQ + nb + qq * 16;
    #pragma unroll
    for (int k = 0; k < 4; ++k) {
        float4 v = make_float4(tile[cl][qq * 16 + k * 4 + 0], tile[cl][qq * 16 + k * 4 + 1],
                               tile[cl][qq * 16 + k * 4 + 2], tile[cl][qq * 16 + k * 4 + 3]);
        *(float4*)&orow[k * 4] = v;
    }
}

// ------------------------------------------------------------------ launch -
extern "C" void kernel_launch(void* const* d_in, const int* in_sizes, int n_in,
                              void* d_out, int out_size, void* d_ws, size_t ws_size,
                              hipStream_t stream)
{
    const float* xyz1    = (const float*)d_in[0];
    const float* xyz2    = (const float*)d_in[1];
    const int*   pid1    = (const int*)d_in[2];
    const int*   pid2    = (const int*)d_in[3];
    const float* points1 = (const float*)d_in[4];
    const float* points2 = (const float*)d_in[5];
    const float* w0      = (const float*)d_in[6];
    const float* g0      = (const float*)d_in[8];
    const float* bt0     = (const float*)d_in[9];
    const float* w1      = (const float*)d_in[10];
    const float* g1      = (const float*)d_in[12];
    const float* bt1     = (const float*)d_in[13];
    float* out = (float*)d_out;

    char* ws = (char*)d_ws;
    int*            boff  = (int*)(ws + 0);                  // 128 B
    float*          sums  = (float*)(ws + 128);              // 4 KB
    float*          sum0  = sums, *sq0 = sums + 256, *sum1 = sums + 512, *sq1 = sums + 768;
    int*            idxb  = (int*)(ws + 8192);               // 192 KB
    float*          wb    = (float*)(ws + 8192 + 196608);    // 192 KB
    unsigned short* Wf0   = (unsigned short*)(ws + 8192 + 393216);   // 256 KB
    unsigned short* Wf1   = (unsigned short*)(ws + 8192 + 655360);   // 128 KB
    float4*         bpts  = (float4*)(ws + 8192 + 786432);   // 64 KB
    unsigned short* p2Tb  = (unsigned short*)(ws + 1048576); // 2 MB
    unsigned short* Xt    = (unsigned short*)(ws + 1048576 + 2097152);            // 16 MB
    unsigned short* y0Tb  = (unsigned short*)(ws + 1048576 + 2097152 + 16777216); // 8 MB
    unsigned short* y1Tb  = (unsigned short*)(ws + 1048576 + 2097152 + 25165824); // 8 MB

    bucket_kernel<<<1, 1024, 0, stream>>>(xyz2, pid2, bpts, boff, sums);
    knn_kernel<<<NQ * 16 / 256, 256, 0, stream>>>(xyz1, pid1, bpts, boff, idxb, wb);
    prep_kernel<<<1472, 256, 0, stream>>>(points1, points2, w0, w1, Xt, p2Tb, Wf0, Wf1);
    interp_kernel<<<NQ * 64 / 256, 256, 0, stream>>>(p2Tb, idxb, wb, Xt);
    mgemm_kernel<512, true><<<NQ / 32, 512, 0, stream>>>(
        Wf0, Xt, nullptr, nullptr, nullptr, nullptr, y0Tb);
    stats_kernel<<<64, 256, 0, stream>>>(y0Tb, sum0, sq0);
    mgemm_kernel<256, false><<<NQ / 32, 512, 0, stream>>>(
        Wf1, y0Tb, sum0, sq0, g0, bt0, y1Tb);
    stats_kernel<<<64, 256, 0, stream>>>(y1Tb, sum1, sq1);
    bnt_kernel<<<dim3(4, NQ / 64), 256, 0, stream>>>(y1Tb, sum1, sq1, g1, bt1, out);
}

// Round 9
// 164.139 us; speedup vs baseline: 1.7188x; 1.0751x over previous
//
#include <hip/hip_runtime.h>
#include <math.h>

#define NQ 16384
#define NS 4096
#define NP 16
#define BIGD 1e8f
#define EPSW 1e-8f

typedef __attribute__((ext_vector_type(8))) short short8;
typedef __attribute__((ext_vector_type(4))) float f32x4;

static __device__ __forceinline__ unsigned short f2bf(float x) {
    unsigned u = __float_as_uint(x);
    unsigned r = (u + 0x7fff + ((u >> 16) & 1)) >> 16;   // RNE
    return (unsigned short)r;
}
static __device__ __forceinline__ float bf2f(unsigned short u) {
    return __uint_as_float(((unsigned)u) << 16);
}

// ------------------------------------------------------- piece bucketing ---
__global__ __launch_bounds__(1024)
void bucket_kernel(const float* __restrict__ xyz2, const int* __restrict__ pid2,
                   float4* __restrict__ bpts, int* __restrict__ boff)
{
    __shared__ int spid[NS];
    __shared__ int segcnt[64][NP];
    __shared__ int segbase[64][NP];
    __shared__ int poff[NP + 1];
    const int t = threadIdx.x;
    for (int i = t; i < NS; i += 1024) spid[i] = pid2[i];
    __syncthreads();
    {
        const int seg = t >> 4, p = t & 15;
        int c = 0;
        const int b = seg * 64;
        for (int i = 0; i < 64; ++i) c += (spid[b + i] == p);
        segcnt[seg][p] = c;
    }
    __syncthreads();
    if (t < NP) {
        int run = 0;
        for (int s = 0; s < 64; ++s) { segbase[s][t] = run; run += segcnt[s][t]; }
        poff[t] = run;
    }
    __syncthreads();
    if (t == 0) {
        int run = 0;
        for (int p = 0; p < NP; ++p) { int c = poff[p]; poff[p] = run; run += c; }
        poff[NP] = run;
    }
    __syncthreads();
    if (t <= NP) boff[t] = poff[t];
    {
        const int seg = t >> 4, p = t & 15;
        int pos = poff[p] + segbase[seg][p];
        const int b = seg * 64;
        for (int i = 0; i < 64; ++i) {
            const int gi = b + i;
            if (spid[gi] == p) {
                bpts[pos] = make_float4(xyz2[gi], xyz2[NS + gi], xyz2[2 * NS + gi],
                                        __int_as_float(gi));
                ++pos;
            }
        }
    }
}

// ---------------------------------------------------------------- KNN ------
#define LEXLT(d, j, e, je) ((d) < (e) || ((d) == (e) && (j) < (je)))

__global__ __launch_bounds__(256)
void knn_kernel(const float* __restrict__ xyz1, const int* __restrict__ pid1,
                const float4* __restrict__ bpts, const int* __restrict__ boff,
                int* __restrict__ oidx, float* __restrict__ ow)
{
    const int t = blockIdx.x * 256 + threadIdx.x;
    const int q = t >> 4;
    const int k = t & 15;
    const float qx = xyz1[q], qy = xyz1[NQ + q], qz = xyz1[2 * NQ + q];
    const int p = pid1[q];
    const int s0 = boff[p], s1 = boff[p + 1];

    float e0 = INFINITY, e1 = INFINITY, e2 = INFINITY;
    int j0 = 0, j1 = 0, j2 = 0;
    for (int i = s0 + k; i < s1; i += 16) {
        float4 pt = bpts[i];
        const float dx = pt.x - qx, dy = pt.y - qy, dz = pt.z - qz;
        const float d = fmaf(dx, dx, fmaf(dy, dy, dz * dz));
        const int oi = __float_as_int(pt.w);
        const bool b0 = LEXLT(d, oi, e0, j0), b1 = LEXLT(d, oi, e1, j1),
                   b2 = LEXLT(d, oi, e2, j2);
        e2 = b2 ? (b1 ? e1 : d) : e2;  j2 = b2 ? (b1 ? j1 : oi) : j2;
        e1 = b1 ? (b0 ? e0 : d) : e1;  j1 = b1 ? (b0 ? j0 : oi) : j1;
        e0 = b0 ? d : e0;              j0 = b0 ? oi : j0;
    }
    #pragma unroll
    for (int m = 1; m <= 8; m <<= 1) {
        float f[3]; int gi[3];
        f[0] = __shfl_xor(e0, m); gi[0] = __shfl_xor(j0, m);
        f[1] = __shfl_xor(e1, m); gi[1] = __shfl_xor(j1, m);
        f[2] = __shfl_xor(e2, m); gi[2] = __shfl_xor(j2, m);
        #pragma unroll
        for (int c = 0; c < 3; ++c) {
            const float d = f[c]; const int oi = gi[c];
            const bool b0 = LEXLT(d, oi, e0, j0), b1 = LEXLT(d, oi, e1, j1),
                       b2 = LEXLT(d, oi, e2, j2);
            e2 = b2 ? (b1 ? e1 : d) : e2;  j2 = b2 ? (b1 ? j1 : oi) : j2;
            e1 = b1 ? (b0 ? e0 : d) : e1;  j1 = b1 ? (b0 ? j0 : oi) : j1;
            e0 = b0 ? d : e0;              j0 = b0 ? oi : j0;
        }
    }
    if (k == 0) {
        if (isinf(e0)) { j0 = 0;  e0 = BIGD; }
        if (isinf(e1)) { j1 = j0; e1 = BIGD; }
        if (isinf(e2)) { j2 = j0; e2 = BIGD; }
        const float w0 = 1.f / (e0 + EPSW), w1 = 1.f / (e1 + EPSW), w2 = 1.f / (e2 + EPSW);
        const float inv = 1.f / (w0 + w1 + w2);
        oidx[q * 3 + 0] = j0; oidx[q * 3 + 1] = j1; oidx[q * 3 + 2] = j2;
        ow[q * 3 + 0] = w0 * inv; ow[q * 3 + 1] = w1 * inv; ow[q * 3 + 2] = w2 * inv;
    }
}

// ----------------------------------------- prep: p2Tb tcvt + W re-layout ---
static __device__ __forceinline__
void wrelay_body(const float* __restrict__ src, unsigned short* __restrict__ dst,
                 int K, int kslog, int o4)
{
    const int e4 = o4 & 1;
    const int tmp = o4 >> 1;
    const int l = tmp & 63;
    const int gks = tmp >> 6;
    const int ks = gks & ((1 << kslog) - 1);
    const int g  = gks >> kslog;
    const int row = g * 16 + (l & 15);
    const int col = ks * 32 + (l >> 4) * 8 + e4 * 4;
    float4 v = *(const float4*)&src[(size_t)row * K + col];
    ushort4 o;
    o.x = f2bf(v.x); o.y = f2bf(v.y); o.z = f2bf(v.z); o.w = f2bf(v.w);
    ((ushort4*)dst)[o4] = o;
}

__global__ __launch_bounds__(256)
void prep_kernel(const float* __restrict__ points2,
                 const float* __restrict__ w0, const float* __restrict__ w1,
                 unsigned short* __restrict__ p2Tb,
                 unsigned short* __restrict__ Wf0, unsigned short* __restrict__ Wf1)
{
    __shared__ float tile[64][65];
    const int b = blockIdx.x, t = threadIdx.x;
    if (b < 256) {
        const int cb = (b & 3) * 64, nb = (b >> 2) * 64;
        #pragma unroll
        for (int rnd = 0; rnd < 4; ++rnd) {
            const int r = rnd * 16 + (t >> 4);
            const int c4 = (t & 15) * 4;
            float4 v = *(const float4*)&points2[(size_t)(cb + r) * NS + nb + c4];
            tile[r][c4 + 0] = v.x; tile[r][c4 + 1] = v.y;
            tile[r][c4 + 2] = v.z; tile[r][c4 + 3] = v.w;
        }
        __syncthreads();
        #pragma unroll
        for (int half = 0; half < 2; ++half) {
            const int p  = (t >> 3) + half * 32;
            const int cg = t & 7;
            ushort4 o0, o1;
            o0.x = f2bf(tile[cg*8+0][p]); o0.y = f2bf(tile[cg*8+1][p]);
            o0.z = f2bf(tile[cg*8+2][p]); o0.w = f2bf(tile[cg*8+3][p]);
            o1.x = f2bf(tile[cg*8+4][p]); o1.y = f2bf(tile[cg*8+5][p]);
            o1.z = f2bf(tile[cg*8+6][p]); o1.w = f2bf(tile[cg*8+7][p]);
            ushort4* d = (ushort4*)&p2Tb[(size_t)(nb + p) * 256 + cb + cg * 8];
            d[0] = o0; d[1] = o1;
        }
    } else if (b < 384) {
        wrelay_body(w0, Wf0, 512, 4, (b - 256) * 256 + t);
    } else {
        wrelay_body(w1, Wf1, 256, 3, (b - 384) * 256 + t);
    }
}

// ---------------------------- GEMM1 fused: X-tile build + MFMA + epilogue --
// 512 blocks x 512 threads. Block owns points [n0,n0+32): stages points1
// slab (transpose+cvt in LDS), interp straight into LDS, K=512 GEMM, then
// LDS epilogue -> coalesced y0 store + per-block BN partials (no atomics).
__global__ __launch_bounds__(512, 4)
void mgemm1f_kernel(const float* __restrict__ points1,
                    const unsigned short* __restrict__ p2Tb,
                    const int* __restrict__ idxb, const float* __restrict__ wb,
                    const unsigned short* __restrict__ Wf0,
                    unsigned short* __restrict__ y0Tb,
                    float* __restrict__ psum, float* __restrict__ psq)
{
    __shared__ unsigned char sX[32768];       // X-tile: 32 rows x 1024B (swizzled)
    __shared__ unsigned char scratch[16896];  // float[128][33] / bf16 y-tile [32][512B]
    const int b = blockIdx.x, t = threadIdx.x;
    const int n0 = b * 32;

    // A: points1 columns -> sX k=[0,256)
    {
        float (*ft)[33] = (float(*)[33])scratch;
        const int j = t & 31, cr = t >> 5;            // cr 0..15
        for (int h = 0; h < 2; ++h) {
            #pragma unroll
            for (int i = 0; i < 8; ++i)
                ft[cr + 16 * i][j] =
                    points1[(size_t)(128 * h + cr + 16 * i) * NQ + n0 + j];
            __syncthreads();
            const int n = t >> 4, cc = t & 15;
            ushort4 lo, hi;
            lo.x = f2bf(ft[cc*8+0][n]); lo.y = f2bf(ft[cc*8+1][n]);
            lo.z = f2bf(ft[cc*8+2][n]); lo.w = f2bf(ft[cc*8+3][n]);
            hi.x = f2bf(ft[cc*8+4][n]); hi.y = f2bf(ft[cc*8+5][n]);
            hi.z = f2bf(ft[cc*8+6][n]); hi.w = f2bf(ft[cc*8+7][n]);
            const int cbyt = h * 256 + cc * 16;
            unsigned char* d = &sX[n * 1024 + (cbyt ^ ((n & 7) << 4))];
            ((ushort4*)d)[0] = lo; ((ushort4*)d)[1] = hi;
            __syncthreads();
        }
    }
    // B: interp -> sX k=[256,512)  (16 channels = 32B per thread)
    {
        const int n = t >> 4, cc = t & 15;
        const int q = n0 + n;
        const int i0 = idxb[q*3+0], i1 = idxb[q*3+1], i2 = idxb[q*3+2];
        const float wa = wb[q*3+0], wv = wb[q*3+1], wc2 = wb[q*3+2];
        const int ch0 = cc * 16;
        const short8 A0 = *(const short8*)&p2Tb[(size_t)i0 * 256 + ch0];
        const short8 A1 = *(const short8*)&p2Tb[(size_t)i0 * 256 + ch0 + 8];
        const short8 B0 = *(const short8*)&p2Tb[(size_t)i1 * 256 + ch0];
        const short8 B1 = *(const short8*)&p2Tb[(size_t)i1 * 256 + ch0 + 8];
        const short8 C0 = *(const short8*)&p2Tb[(size_t)i2 * 256 + ch0];
        const short8 C1 = *(const short8*)&p2Tb[(size_t)i2 * 256 + ch0 + 8];
        unsigned short us[16];
        #pragma unroll
        for (int e = 0; e < 8; ++e) {
            us[e]     = f2bf(wa * bf2f((unsigned short)A0[e]) +
                             wv * bf2f((unsigned short)B0[e]) +
                             wc2 * bf2f((unsigned short)C0[e]));
            us[8 + e] = f2bf(wa * bf2f((unsigned short)A1[e]) +
                             wv * bf2f((unsigned short)B1[e]) +
                             wc2 * bf2f((unsigned short)C1[e]));
        }
        const int cb1 = 512 + cc * 32;
        unsigned char* d0 = &sX[n * 1024 + (cb1 ^ ((n & 7) << 4))];
        ((ushort4*)d0)[0] = make_ushort4(us[0], us[1], us[2], us[3]);
        ((ushort4*)d0)[1] = make_ushort4(us[4], us[5], us[6], us[7]);
        unsigned char* d1 = &sX[n * 1024 + ((cb1 + 16) ^ ((n & 7) << 4))];
        ((ushort4*)d1)[0] = make_ushort4(us[8], us[9], us[10], us[11]);
        ((ushort4*)d1)[1] = make_ushort4(us[12], us[13], us[14], us[15]);
    }
    __syncthreads();

    // C: GEMM K=512
    const int w = t >> 6, l = t & 63, lr = l & 15, lk = l >> 4;
    f32x4 acc[2][2] = {};
    #pragma unroll
    for (int ks = 0; ks < 16; ++ks) {
        short8 bfv[2];
        #pragma unroll
        for (int nf = 0; nf < 2; ++nf) {
            const int r = nf * 16 + lr;
            const int cbyte = ks * 64 + lk * 16;
            bfv[nf] = *(const short8*)&sX[r * 1024 + (cbyte ^ ((r & 7) << 4))];
        }
        #pragma unroll
        for (int mf = 0; mf < 2; ++mf) {
            const short8 a = *(const short8*)(
                Wf0 + (((size_t)(w * 2 + mf) * 16 + ks) * 64 + l) * 8);
            #pragma unroll
            for (int nf = 0; nf < 2; ++nf)
                acc[mf][nf] = __builtin_amdgcn_mfma_f32_16x16x32_bf16(
                                  a, bfv[nf], acc[mf][nf], 0, 0, 0);
        }
    }
    __syncthreads();                          // done reading scratch? (ft free)

    // D: epilogue via LDS tile (swizzled [n][512B])
    unsigned char* yt = scratch;
    #pragma unroll
    for (int mf = 0; mf < 2; ++mf)
        #pragma unroll
        for (int nf = 0; nf < 2; ++nf) {
            const int m = w * 32 + mf * 16 + lk * 4;
            const int n = nf * 16 + lr;
            ushort4 o;
            o.x = f2bf(acc[mf][nf][0]); o.y = f2bf(acc[mf][nf][1]);
            o.z = f2bf(acc[mf][nf][2]); o.w = f2bf(acc[mf][nf][3]);
            *(ushort4*)&yt[n * 512 + ((m * 2) ^ ((n & 7) << 4))] = o;
        }
    __syncthreads();
    {   // coalesced store: 32B per thread
        const int n = t >> 4, cB = (t & 15) * 32;
        ushort4 v0a = *(ushort4*)&yt[n * 512 + ((cB)      ^ ((n & 7) << 4))];
        ushort4 v0b = *(ushort4*)&yt[n * 512 + ((cB + 8)  ^ ((n & 7) << 4))];
        ushort4 v1a = *(ushort4*)&yt[n * 512 + ((cB + 16) ^ ((n & 7) << 4))];
        ushort4 v1b = *(ushort4*)&yt[n * 512 + ((cB + 24) ^ ((n & 7) << 4))];
        ushort4* dst = (ushort4*)&y0Tb[(size_t)(n0 + n) * 256 + (t & 15) * 16];
        dst[0] = v0a; dst[1] = v0b; dst[2] = v1a; dst[3] = v1b;
    }
    if (t < 256) {                            // per-block BN partials
        float s = 0.f, q = 0.f;
        #pragma unroll 8
        for (int n = 0; n < 32; ++n) {
            const float f = bf2f(*(const unsigned short*)
                &yt[n * 512 + ((t * 2) ^ ((n & 7) << 4))]);
            s += f; q += f * f;
        }
        psum[b * 256 + t] = s; psq[b * 256 + t] = q;
    }
}

// --------------------- reduce partials -> BN scale/shift (256 blocks) ------
__global__ __launch_bounds__(256)
void red_kernel(const float* __restrict__ psum, const float* __restrict__ psq,
                const float* __restrict__ g, const float* __restrict__ bt,
                float* __restrict__ gsc, float* __restrict__ gsh)
{
    const int c = blockIdx.x, t = threadIdx.x;
    float s = psum[(size_t)t * 256 + c] + psum[(size_t)(t + 256) * 256 + c];
    float q = psq [(size_t)t * 256 + c] + psq [(size_t)(t + 256) * 256 + c];
    #pragma unroll
    for (int off = 32; off; off >>= 1) {
        s += __shfl_down(s, off); q += __shfl_down(q, off);
    }
    __shared__ float sr[4], qr[4];
    if ((t & 63) == 0) { sr[t >> 6] = s; qr[t >> 6] = q; }
    __syncthreads();
    if (t == 0) {
        float S = sr[0] + sr[1] + sr[2] + sr[3];
        float Q = qr[0] + qr[1] + qr[2] + qr[3];
        const float mean = S * (1.f / NQ);
        const float var  = Q * (1.f / NQ) - mean * mean;
        const float rs = rsqrtf(var + 1e-5f);
        const float sc = g[c] * rs;
        gsc[c] = sc; gsh[c] = bt[c] - mean * sc;
    }
}

// ----------------- GEMM2 fused: BN1+relu reg-stage + MFMA + epilogue -------
__global__ __launch_bounds__(512, 4)
void mgemm2f_kernel(const unsigned short* __restrict__ Wf1,
                    const unsigned short* __restrict__ y0Tb,
                    const float* __restrict__ gsc, const float* __restrict__ gsh,
                    unsigned short* __restrict__ y1Tb,
                    float* __restrict__ psum, float* __restrict__ psq)
{
    __shared__ unsigned char sB[32 * 512];
    __shared__ unsigned char yts[16384];
    __shared__ float scs[256], shs[256];
    const int b = blockIdx.x, t = threadIdx.x;
    const int n0 = b * 32;
    if (t < 256) { scs[t] = gsc[t]; shs[t] = gsh[t]; }
    __syncthreads();
    {   // reg-stage B with BN1+relu (16 channels = 32B per thread)
        const int row = t >> 4;
        const int ch0 = (t & 15) * 16;
        const short8 v0 = *(const short8*)&y0Tb[(size_t)(n0 + row) * 256 + ch0];
        const short8 v1 = *(const short8*)&y0Tb[(size_t)(n0 + row) * 256 + ch0 + 8];
        unsigned short us[16];
        #pragma unroll
        for (int e = 0; e < 8; ++e) {
            us[e]     = f2bf(fmaxf(fmaf(bf2f((unsigned short)v0[e]),
                                        scs[ch0 + e], shs[ch0 + e]), 0.f));
            us[8 + e] = f2bf(fmaxf(fmaf(bf2f((unsigned short)v1[e]),
                                        scs[ch0 + 8 + e], shs[ch0 + 8 + e]), 0.f));
        }
        const int cb0 = ch0 * 2;
        unsigned char* d0 = &sB[row * 512 + (cb0 ^ ((row & 7) << 4))];
        ((ushort4*)d0)[0] = make_ushort4(us[0], us[1], us[2], us[3]);
        ((ushort4*)d0)[1] = make_ushort4(us[4], us[5], us[6], us[7]);
        unsigned char* d1 = &sB[row * 512 + ((cb0 + 16) ^ ((row & 7) << 4))];
        ((ushort4*)d1)[0] = make_ushort4(us[8], us[9], us[10], us[11]);
        ((ushort4*)d1)[1] = make_ushort4(us[12], us[13], us[14], us[15]);
    }
    __syncthreads();

    const int w = t >> 6, l = t & 63, lr = l & 15, lk = l >> 4;
    f32x4 acc[2][2] = {};
    #pragma unroll
    for (int ks = 0; ks < 8; ++ks) {
        short8 bfv[2];
        #pragma unroll
        for (int nf = 0; nf < 2; ++nf) {
            const int r = nf * 16 + lr;
            const int cbyte = ks * 64 + lk * 16;
            bfv[nf] = *(const short8*)&sB[r * 512 + (cbyte ^ ((r & 7) << 4))];
        }
        #pragma unroll
        for (int mf = 0; mf < 2; ++mf) {
            const short8 a = *(const short8*)(
                Wf1 + (((size_t)(w * 2 + mf) * 8 + ks) * 64 + l) * 8);
            #pragma unroll
            for (int nf = 0; nf < 2; ++nf)
                acc[mf][nf] = __builtin_amdgcn_mfma_f32_16x16x32_bf16(
                                  a, bfv[nf], acc[mf][nf], 0, 0, 0);
        }
    }
    // epilogue via LDS tile
    unsigned char* yt = yts;
    #pragma unroll
    for (int mf = 0; mf < 2; ++mf)
        #pragma unroll
        for (int nf = 0; nf < 2; ++nf) {
            const int m = w * 32 + mf * 16 + lk * 4;
            const int n = nf * 16 + lr;
            ushort4 o;
            o.x = f2bf(acc[mf][nf][0]); o.y = f2bf(acc[mf][nf][1]);
            o.z = f2bf(acc[mf][nf][2]); o.w = f2bf(acc[mf][nf][3]);
            *(ushort4*)&yt[n * 512 + ((m * 2) ^ ((n & 7) << 4))] = o;
        }
    __syncthreads();
    {
        const int n = t >> 4, cB = (t & 15) * 32;
        ushort4 v0a = *(ushort4*)&yt[n * 512 + ((cB)      ^ ((n & 7) << 4))];
        ushort4 v0b = *(ushort4*)&yt[n * 512 + ((cB + 8)  ^ ((n & 7) << 4))];
        ushort4 v1a = *(ushort4*)&yt[n * 512 + ((cB + 16) ^ ((n & 7) << 4))];
        ushort4 v1b = *(ushort4*)&yt[n * 512 + ((cB + 24) ^ ((n & 7) << 4))];
        ushort4* dst = (ushort4*)&y1Tb[(size_t)(n0 + n) * 256 + (t & 15) * 16];
        dst[0] = v0a; dst[1] = v0b; dst[2] = v1a; dst[3] = v1b;
    }
    if (t < 256) {
        float s = 0.f, q = 0.f;
        #pragma unroll 8
        for (int n = 0; n < 32; ++n) {
            const float f = bf2f(*(const unsigned short*)
                &yt[n * 512 + ((t * 2) ^ ((n & 7) << 4))]);
            s += f; q += f * f;
        }
        psum[b * 256 + t] = s; psq[b * 256 + t] = q;
    }
}

// --------------- final: BN2 + relu + transpose [N][256] -> out [256][NQ] ---
__global__ __launch_bounds__(256)
void bnt_kernel(const unsigned short* __restrict__ Y, const float* __restrict__ gsc,
                const float* __restrict__ gsh, float* __restrict__ out)
{
    __shared__ float tile[64][65];
    __shared__ float scs[64], shs[64];
    const int t = threadIdx.x;
    const int cb = blockIdx.x * 64;
    const int nb = blockIdx.y * 64;
    if (t < 64) { scs[t] = gsc[cb + t]; shs[t] = gsh[cb + t]; }
    __syncthreads();
    #pragma unroll
    for (int rnd = 0; rnd < 4; ++rnd) {
        const int nl = rnd * 16 + (t >> 4);
        const int c4 = (t & 15) * 4;
        ushort4 v = *(const ushort4*)&Y[(size_t)(nb + nl) * 256 + cb + c4];
        tile[c4 + 0][nl] = fmaxf(fmaf(bf2f(v.x), scs[c4 + 0], shs[c4 + 0]), 0.f);
        tile[c4 + 1][nl] = fmaxf(fmaf(bf2f(v.y), scs[c4 + 1], shs[c4 + 1]), 0.f);
        tile[c4 + 2][nl] = fmaxf(fmaf(bf2f(v.z), scs[c4 + 2], shs[c4 + 2]), 0.f);
        tile[c4 + 3][nl] = fmaxf(fmaf(bf2f(v.w), scs[c4 + 3], shs[c4 + 3]), 0.f);
    }
    __syncthreads();
    const int cl = t >> 2, qq = t & 3;
    float* orow = out + (size_t)(cb + cl) * NQ + nb + qq * 16;
    #pragma unroll
    for (int k = 0; k < 4; ++k) {
        float4 v = make_float4(tile[cl][qq * 16 + k * 4 + 0], tile[cl][qq * 16 + k * 4 + 1],
                               tile[cl][qq * 16 + k * 4 + 2], tile[cl][qq * 16 + k * 4 + 3]);
        *(float4*)&orow[k * 4] = v;
    }
}

// ------------------------------------------------------------------ launch -
extern "C" void kernel_launch(void* const* d_in, const int* in_sizes, int n_in,
                              void* d_out, int out_size, void* d_ws, size_t ws_size,
                              hipStream_t stream)
{
    const float* xyz1    = (const float*)d_in[0];
    const float* xyz2    = (const float*)d_in[1];
    const int*   pid1    = (const int*)d_in[2];
    const int*   pid2    = (const int*)d_in[3];
    const float* points1 = (const float*)d_in[4];
    const float* points2 = (const float*)d_in[5];
    const float* w0      = (const float*)d_in[6];
    const float* g0      = (const float*)d_in[8];
    const float* bt0     = (const float*)d_in[9];
    const float* w1      = (const float*)d_in[10];
    const float* g1      = (const float*)d_in[12];
    const float* bt1     = (const float*)d_in[13];
    float* out = (float*)d_out;

    char* ws = (char*)d_ws;
    int*            boff  = (int*)(ws + 0);                  // 128 B
    int*            idxb  = (int*)(ws + 8192);               // 192 KB
    float*          wb    = (float*)(ws + 204800);           // 192 KB
    unsigned short* Wf0   = (unsigned short*)(ws + 401408);  // 256 KB
    unsigned short* Wf1   = (unsigned short*)(ws + 663552);  // 128 KB
    float4*         bpts  = (float4*)(ws + 794624);          // 64 KB
    float*          psum0 = (float*)(ws + 860160);           // 512 KB
    float*          psq0  = (float*)(ws + 1384448);          // 512 KB
    float*          psum1 = (float*)(ws + 1908736);          // 512 KB
    float*          psq1  = (float*)(ws + 2433024);          // 512 KB
    float*          gsc0  = (float*)(ws + 2957312);
    float*          gsh0  = (float*)(ws + 2958336);
    float*          gsc1  = (float*)(ws + 2959360);
    float*          gsh1  = (float*)(ws + 2960384);
    unsigned short* p2Tb  = (unsigned short*)(ws + 3145728); // 2 MB
    unsigned short* y0Tb  = (unsigned short*)(ws + 5242880); // 8 MB
    unsigned short* y1Tb  = (unsigned short*)(ws + 13631488);// 8 MB

    bucket_kernel<<<1, 1024, 0, stream>>>(xyz2, pid2, bpts, boff);
    knn_kernel<<<NQ * 16 / 256, 256, 0, stream>>>(xyz1, pid1, bpts, boff, idxb, wb);
    prep_kernel<<<448, 256, 0, stream>>>(points2, w0, w1, p2Tb, Wf0, Wf1);
    mgemm1f_kernel<<<NQ / 32, 512, 0, stream>>>(points1, p2Tb, idxb, wb, Wf0,
                                                y0Tb, psum0, psq0);
    red_kernel<<<256, 256, 0, stream>>>(psum0, psq0, g0, bt0, gsc0, gsh0);
    mgemm2f_kernel<<<NQ / 32, 512, 0, stream>>>(Wf1, y0Tb, gsc0, gsh0,
                                                y1Tb, psum1, psq1);
    red_kernel<<<256, 256, 0, stream>>>(psum1, psq1, g1, bt1, gsc1, gsh1);
    bnt_kernel<<<dim3(4, NQ / 64), 256, 0, stream>>>(y1Tb, gsc1, gsh1, out);
}